// Round 4
// baseline (507.556 us; speedup 1.0000x reference)
//
#include <hip/hip_runtime.h>
#include <hip/hip_bf16.h>
#include <cstdint>

typedef unsigned short u16;
typedef __bf16 bf16x8 __attribute__((ext_vector_type(8)));
typedef float  f32x4  __attribute__((ext_vector_type(4)));

typedef const __attribute__((address_space(1))) void* gptr_t;
typedef __attribute__((address_space(3))) void*       sptr_t;

#define IN_DIM  1024
#define OUT_DIM 2048
#define NROWS   8192            // 4*2048 samples
#define NB      8               // GRID + K   (basis functions per d)
#define KTOT    (IN_DIM * 9)    // 9216: k<8192 -> spline d*8+g ; k>=8192 -> silu d
#define KSPL    (IN_DIM * 8)    // 8192

#define WT_O 16                 // wt transpose tile: 16 o x 64 d
#define WT_D 64
#define TR_BLOCKS ((NROWS / 64) * (IN_DIM / 64))        // 2048 x-transpose blocks (tier-2)
#define WT_BLOCKS ((OUT_DIM / WT_O) * (IN_DIM / WT_D))  // 2048 wt blocks
#define ACT_BLOCKS ((NROWS / 64) * (IN_DIM / 64))       // 2048 act-build blocks (tier-1)

// Tier-1 GEMM geometry: 256x256 tile, BK=32, 4-deep K-tile pipeline.
#define BK 32
#define TILE_U16 (256 * BK)     // 8192 u16 = 16 KB per K-tile buffer (per matrix)
#define NKT (KTOT / BK)         // 288

__device__ __forceinline__ float rcp_fast(float v) { return __builtin_amdgcn_rcpf(v); }

// fp32 -> bf16 round-to-nearest-even bit pattern (finite inputs only)
__device__ __forceinline__ u16 f2b(float v) {
  uint32_t u = __float_as_uint(v);
  uint32_t r = (u + 0x7FFFu + ((u >> 16) & 1u)) >> 16;
  return (u16)r;
}

// pack two fp32 -> packed bf16x2 (a in low half), RNE
__device__ __forceinline__ uint32_t pkbf(float a, float b) {
  return (uint32_t)f2b(a) | ((uint32_t)f2b(b) << 16);
}

// Uniform-knot cardinal cubic: 8 spline channels for one x, packed as 4x u32
// (bf16 pairs, channel g ascending). j=floor((x+1)*2.5) in [0,4], u=frac;
// nonzero channels j..j+3 = {(1-u)^3, 3u^3-6u^2+4, -3u^3+3u^2+3u+1, u^3}/6.
__device__ __forceinline__ uint4 basis_pack(float xval) {
  float tt = (xval + 1.0f) * 2.5f;
  float jf = floorf(tt);
  jf = fminf(fmaxf(jf, 0.0f), 4.0f);
  const float u = tt - jf;
  const int j = (int)jf;
  const float um = 1.0f - u;
  const float u2 = u * u, u3 = u2 * u;
  const float b0 = um * um * um * (1.0f / 6.0f);
  const float b1 = (3.0f * u3 - 6.0f * u2 + 4.0f) * (1.0f / 6.0f);
  const float b2 = (-3.0f * u3 + 3.0f * u2 + 3.0f * u + 1.0f) * (1.0f / 6.0f);
  const float b3 = u3 * (1.0f / 6.0f);
  const uint32_t e01 = pkbf(b0, b1), e23 = pkbf(b2, b3);
  const uint32_t o0 = e01 << 16;                      // (0, h0)
  const uint32_t o12 = (e01 >> 16) | (e23 << 16);     // (h1, h2)
  const uint32_t o3 = e23 >> 16;                      // (h3, 0)
  const int odd = j & 1, m = j >> 1;
  const uint32_t a0 = odd ? o0 : e01;
  const uint32_t a1 = odd ? o12 : e23;
  const uint32_t a2 = odd ? o3 : 0u;
  uint4 wv;
  wv.x = (m == 0) ? a0 : 0u;
  wv.y = (m == 1) ? a0 : ((m == 0) ? a1 : 0u);
  wv.z = (m == 2) ? a0 : ((m == 1) ? a1 : ((m == 0) ? a2 : 0u));
  wv.w = (m == 2) ? a1 : ((m == 1) ? a2 : 0u);
  return wv;
}

// ---------------------------------------------------------------------------
// TIER-1 prep: blocks [0,ACT_BLOCKS) materialize act[n][k] bf16
// (k<8192: spline basis d*8+g ; k>=8192: silu(x[n][d])). Blocks
// [ACT_BLOCKS,+WT_BLOCKS) build Wt[o][k] (coef*scale_sp / scale_base) bf16.
// (Unchanged this round to isolate the gemm schedule delta.)
// ---------------------------------------------------------------------------
__global__ __launch_bounds__(256) void kan_prep2(const float* __restrict__ x,
                                                 const float* __restrict__ coef,
                                                 const float* __restrict__ scale_base,
                                                 const float* __restrict__ scale_sp,
                                                 u16* __restrict__ act,
                                                 u16* __restrict__ wt) {
  const int t = threadIdx.x;

  if (blockIdx.x < ACT_BLOCKS) {
    // ---- act tile: 64 n x 64 d ----
    __shared__ __align__(16) u16 st[64][72];   // silu staging (pad 72 breaks banks)
    const int bi = blockIdx.x;
    const int n0 = (bi & 127) * 64;
    const int d0 = (bi >> 7) * 64;
    const int dl = t & 63, r0 = t >> 6;        // r0 in 0..3
#pragma unroll
    for (int i = 0; i < 16; ++i) {
      const int r = r0 + i * 4;
      const float v = x[(size_t)(n0 + r) * IN_DIM + d0 + dl];
      *(uint4*)&act[(size_t)(n0 + r) * KTOT + (size_t)(d0 + dl) * 8] = basis_pack(v);
      st[r][dl] = f2b(v * rcp_fast(1.0f + __expf(-v)));
    }
    __syncthreads();
#pragma unroll
    for (int j = 0; j < 2; ++j) {
      const int idx = t + j * 256;
      const int r = idx >> 3, c8 = idx & 7;
      *(uint4*)&act[(size_t)(n0 + r) * KTOT + KSPL + d0 + c8 * 8] =
          *(const uint4*)&st[r][c8 * 8];
    }
  } else {
    // ---- Wt path: 16o x 64d transpose tile ----
    __shared__ __align__(16) u16 tsp[WT_O][WT_D * 8 + 8];
    __shared__ __align__(16) u16 tsi[WT_O][WT_D + 8];
    const int bi = blockIdx.x - ACT_BLOCKS;
    const int o0 = (bi % (OUT_DIM / WT_O)) * WT_O;
    const int d0 = (bi / (OUT_DIM / WT_O)) * WT_D;
    const int ol = t & (WT_O - 1), dl0 = t >> 4;  // dl0 in 0..15
#pragma unroll
    for (int rep = 0; rep < WT_D / 16; ++rep) {
      const int dl = rep * 16 + dl0;
      const int d = d0 + dl, o = o0 + ol;
      const size_t doff = (size_t)d * OUT_DIM + o;
      const float ssp = scale_sp[doff];
      const float sbv = scale_base[doff];
      const float4* cp = (const float4*)(coef + doff * 8);
      float4 c0 = cp[0], c1 = cp[1];
      uint4 val;
      val.x = pkbf(c0.x * ssp, c0.y * ssp);
      val.y = pkbf(c0.z * ssp, c0.w * ssp);
      val.z = pkbf(c1.x * ssp, c1.y * ssp);
      val.w = pkbf(c1.z * ssp, c1.w * ssp);
      *(uint4*)&tsp[ol][dl * 8] = val;
      tsi[ol][dl] = f2b(sbv);
    }
    __syncthreads();
    for (int i = t; i < WT_O * 64; i += 256) {
      const int row = i >> 6, col = i & 63;
      *(uint4*)(wt + (size_t)(o0 + row) * KTOT + (size_t)(d0 + col) * 8) =
          *(const uint4*)&tsp[row][col * 8];
    }
    if (t < WT_O * 8) {
      const int row = t >> 3, col = t & 7;
      *(uint4*)(wt + (size_t)(o0 + row) * KTOT + KSPL + d0 + col * 8) =
          *(const uint4*)&tsi[row][col * 8];
    }
  }
}

// ---------------------------------------------------------------------------
// TIER-1 GEMM: C[8192x2048] = act * Wt^T, pure bf16 MFMA GEMM.
// m201-style 2-phase/K-tile schedule: each phase = {ds_read frags for THIS
// phase's MFMAs; [stage / counted vmcnt]; barrier; lgkmcnt(0); setprio(1);
// 16 MFMA; setprio(0); barrier}. Phase p+1's ds_reads execute while the
// matrix pipe drains phase p's MFMA backlog -> LDS and MFMA pipes overlap
// (this was the m198->m201 +35% lever; our R3 region structure serialized
// them: 2450 cyc/step = 1242 MFMA + 1156 LDS measured).
// 4 LDS buffers, stage distance 3 (same-phase reads force <=3; WAR ledger:
// buf[(T-1)&3]'s last reads finish at PB(T-1) lgkm(0), before the barrier
// preceding STAGE(T+3)). PB(T) waits vmcnt(8) -> tile T+1 landed.
// ---------------------------------------------------------------------------
__global__ __launch_bounds__(512, 2) void kan_gemm2(const u16* __restrict__ act,
                                                    const u16* __restrict__ Bt,
                                                    float* __restrict__ C) {
  __shared__ __align__(16) u16 As[4 * TILE_U16];  // 64 KB
  __shared__ __align__(16) u16 Bs[4 * TILE_U16];  // 64 KB
  const int tid  = threadIdx.x;
  const int lane = tid & 63;
  const int w    = tid >> 6;            // 0..7
  const int wm   = w >> 2, wn = w & 3;  // 2 x 4 wave grid
  const int q    = lane >> 4, m16 = lane & 15;

  // Bijective XCD swizzle: 256 wgs = 8 XCDs x 32; gx fastest so the 8 blocks
  // sharing an A row-panel land on one XCD's L2.
  const int bid = (blockIdx.x & 7) * 32 + (blockIdx.x >> 3);
  const int gx = bid & 7;    // o-tile   (N/256 = 8)
  const int gy = bid >> 3;   // row-tile (M/256 = 32)

  f32x4 acc[8][4];
#pragma unroll
  for (int i = 0; i < 8; ++i)
#pragma unroll
    for (int j = 0; j < 4; ++j) acc[i][j] = (f32x4){0.f, 0.f, 0.f, 0.f};

  // Staging: per K-tile each matrix is 256x32 bf16 = 16 KB = 16 wave-issues;
  // wave w covers rows [w*32, w*32+32) via 2 issues of 16 rows (1 KB each).
  // Lane l -> row w*32 + i*16 + (l>>2), phys chunk l&3; source logical chunk
  // = (l&3) ^ ((row>>1)&3) = (l&3) ^ ((l>>3)&3)  (w,i terms vanish mod 4).
  const int rA  = lane >> 2;
  const int csw = ((lane & 3) ^ ((lane >> 3) & 3)) * 8;  // u16 offset
  const u16* gA = act + (size_t)(gy * 256 + w * 32 + rA) * KTOT + csw;
  const u16* gB = Bt  + (size_t)(gx * 256 + w * 32 + rA) * KTOT + csw;
  const int ldsw = w * 1024;  // u16 offset of this wave's 32-row segment

#define STAGE(T)                                                               \
  do {                                                                         \
    const int _buf = (T) & 3;                                                  \
    const size_t _k0 = (size_t)(T) * BK;                                       \
    const u16* _ga = gA + _k0;                                                 \
    const u16* _gb = gB + _k0;                                                 \
    u16* _la = &As[_buf * TILE_U16 + ldsw];                                    \
    u16* _lb = &Bs[_buf * TILE_U16 + ldsw];                                    \
    __builtin_amdgcn_global_load_lds((gptr_t)_ga, (sptr_t)_la, 16, 0, 0);      \
    __builtin_amdgcn_global_load_lds((gptr_t)(_ga + (size_t)16 * KTOT),        \
                                     (sptr_t)(_la + 512), 16, 0, 0);           \
    __builtin_amdgcn_global_load_lds((gptr_t)_gb, (sptr_t)_lb, 16, 0, 0);      \
    __builtin_amdgcn_global_load_lds((gptr_t)(_gb + (size_t)16 * KTOT),        \
                                     (sptr_t)(_lb + 512), 16, 0, 0);           \
  } while (0)

  // Fragment reads: row base (wm*128 | wn*64) + frag*16 + m16, phys chunk
  // q ^ ((m16>>1)&3) (frag-independent since frag*16 is 0 mod 4 after >>1).
  const int px8 = (q ^ ((m16 >> 1) & 3)) * 8;
  const int aoff = (wm * 128 + m16) * 32 + px8;
  const int boff = (wn * 64 + m16) * 32 + px8;

  bf16x8 fa[4], fb[4];

  // Phase A of tile T: read fa(mt 0-3) + fb, stage T+3, barrier, 16 MFMA.
#define PHASE_A(T, DOSTAGE)                                                    \
  do {                                                                         \
    const u16* _Ab = &As[((T) & 3) * TILE_U16 + aoff];                         \
    const u16* _Bb = &Bs[((T) & 3) * TILE_U16 + boff];                         \
    _Pragma("unroll") for (int i = 0; i < 4; ++i)                              \
        fa[i] = *(const bf16x8*)&_Ab[i * 512];                                 \
    _Pragma("unroll") for (int i = 0; i < 4; ++i)                              \
        fb[i] = *(const bf16x8*)&_Bb[i * 512];                                 \
    if (DOSTAGE) STAGE((T) + 3);                                               \
    asm volatile("" ::: "memory");                                             \
    __builtin_amdgcn_s_barrier();                                              \
    asm volatile("s_waitcnt lgkmcnt(0)" ::: "memory");                         \
    __builtin_amdgcn_s_setprio(1);                                             \
    _Pragma("unroll") for (int mt = 0; mt < 4; ++mt)                           \
      _Pragma("unroll") for (int nt = 0; nt < 4; ++nt)                         \
        acc[mt][nt] = __builtin_amdgcn_mfma_f32_16x16x32_bf16(                 \
            fa[mt], fb[nt], acc[mt][nt], 0, 0, 0);                             \
    __builtin_amdgcn_s_setprio(0);                                             \
    asm volatile("" ::: "memory");                                             \
    __builtin_amdgcn_s_barrier();                                              \
    asm volatile("" ::: "memory");                                             \
  } while (0)

  // Phase B of tile T: read fa(mt 4-7), counted vmcnt (tile T+1 landed),
  // barrier, 16 MFMA (fb persists from phase A).
#define PHASE_B(T, VM)                                                         \
  do {                                                                         \
    const u16* _Ab = &As[((T) & 3) * TILE_U16 + aoff + 2048];                  \
    _Pragma("unroll") for (int i = 0; i < 4; ++i)                              \
        fa[i] = *(const bf16x8*)&_Ab[i * 512];                                 \
    asm volatile("s_waitcnt vmcnt(" #VM ")" ::: "memory");                     \
    __builtin_amdgcn_s_barrier();                                              \
    asm volatile("s_waitcnt lgkmcnt(0)" ::: "memory");                         \
    __builtin_amdgcn_s_setprio(1);                                             \
    _Pragma("unroll") for (int mt = 0; mt < 4; ++mt)                           \
      _Pragma("unroll") for (int nt = 0; nt < 4; ++nt)                         \
        acc[4 + mt][nt] = __builtin_amdgcn_mfma_f32_16x16x32_bf16(             \
            fa[mt], fb[nt], acc[4 + mt][nt], 0, 0, 0);                         \
    __builtin_amdgcn_s_setprio(0);                                             \
    asm volatile("" ::: "memory");                                             \
    __builtin_amdgcn_s_barrier();                                              \
    asm volatile("" ::: "memory");                                             \
  } while (0)

  // Prologue: stage tiles 0..2 (12 loads/thread); tile 0 landed at vmcnt(8).
  STAGE(0);
  STAGE(1);
  STAGE(2);
  asm volatile("s_waitcnt vmcnt(8)" ::: "memory");
  __builtin_amdgcn_s_barrier();
  asm volatile("" ::: "memory");

  // Steady: tiles 0..283 (71 x 4, buffer index folds to j).
  for (int tb = 0; tb < 71; ++tb) {
#pragma unroll
    for (int j = 0; j < 4; ++j) {
      const int t = tb * 4 + j;
      PHASE_A(t, true);
      PHASE_B(t, 8);
    }
  }
  // Tile 284 stages 287 (last); then drain 8 -> 4 -> 0.
  PHASE_A(284, true);
  PHASE_B(284, 8);
  PHASE_A(285, false);
  PHASE_B(285, 4);
  PHASE_A(286, false);
  PHASE_B(286, 0);
  PHASE_A(287, false);
  PHASE_B(287, 0);

#undef PHASE_A
#undef PHASE_B
#undef STAGE

  // Epilogue: C/D layout col = lane&15, row = (lane>>4)*4 + reg (m89-verified)
  const int row_base = gy * 256 + wm * 128 + q * 4;
  const int col_base = gx * 256 + wn * 64 + m16;
#pragma unroll
  for (int mt = 0; mt < 8; ++mt) {
#pragma unroll
    for (int nt = 0; nt < 4; ++nt) {
      const int r0 = row_base + mt * 16;
      const int c  = col_base + nt * 16;
#pragma unroll
      for (int r = 0; r < 4; ++r)
        C[(size_t)(r0 + r) * OUT_DIM + c] = acc[mt][nt][r];
    }
  }
}

// ---------------------------------------------------------------------------
// TIER-2 (previous session's best, ws >= 88MB): on-the-fly A, 128^2 tile.
// ---------------------------------------------------------------------------
__global__ __launch_bounds__(256) void kan_prep(const float* __restrict__ x,
                                                const float* __restrict__ coef,
                                                const float* __restrict__ scale_base,
                                                const float* __restrict__ scale_sp,
                                                float* __restrict__ xT,
                                                u16* __restrict__ sil,
                                                u16* __restrict__ wt) {
  const int t = threadIdx.x;

  if (blockIdx.x < TR_BLOCKS) {
    __shared__ float tile[64][65];
    const int bi = blockIdx.x;
    const int n0 = (bi & 127) * 64;
    const int d0 = (bi >> 7) * 64;
    const int col = t & 63, rbase = t >> 6;
#pragma unroll
    for (int i = 0; i < 16; ++i) {
      const int r = rbase + i * 4;
      const float v = x[(size_t)(n0 + r) * IN_DIM + d0 + col];
      tile[r][col] = v;
      sil[(size_t)(n0 + r) * IN_DIM + d0 + col] =
          f2b(v * rcp_fast(1.0f + __expf(-v)));
    }
    __syncthreads();
#pragma unroll
    for (int i = 0; i < 16; ++i) {
      const int dd = rbase + i * 4;
      xT[(size_t)(d0 + dd) * NROWS + n0 + col] = tile[col][dd];
    }
  } else {
    __shared__ __align__(16) u16 tsp[WT_O][WT_D * 8 + 8];
    __shared__ __align__(16) u16 tsi[WT_O][WT_D + 8];
    const int bi = blockIdx.x - TR_BLOCKS;
    const int o0 = (bi % (OUT_DIM / WT_O)) * WT_O;
    const int d0 = (bi / (OUT_DIM / WT_O)) * WT_D;
    const int ol = t & (WT_O - 1), dl0 = t >> 4;
#pragma unroll
    for (int rep = 0; rep < WT_D / 16; ++rep) {
      const int dl = rep * 16 + dl0;
      const int d = d0 + dl, o = o0 + ol;
      const size_t doff = (size_t)d * OUT_DIM + o;
      const float ssp = scale_sp[doff];
      const float sbv = scale_base[doff];
      const float4* cp = (const float4*)(coef + doff * 8);
      float4 c0 = cp[0], c1 = cp[1];
      uint4 val;
      val.x = pkbf(c0.x * ssp, c0.y * ssp);
      val.y = pkbf(c0.z * ssp, c0.w * ssp);
      val.z = pkbf(c1.x * ssp, c1.y * ssp);
      val.w = pkbf(c1.z * ssp, c1.w * ssp);
      *(uint4*)&tsp[ol][dl * 8] = val;
      tsi[ol][dl] = f2b(sbv);
    }
    __syncthreads();
    for (int i = t; i < WT_O * 64; i += 256) {
      const int row = i >> 6, col = i & 63;
      *(uint4*)(wt + (size_t)(o0 + row) * KTOT + (size_t)(d0 + col) * 8) =
          *(const uint4*)&tsp[row][col * 8];
    }
    if (t < WT_O * 8) {
      const int row = t >> 3, col = t & 7;
      *(uint4*)(wt + (size_t)(o0 + row) * KTOT + KSPL + d0 + col * 8) =
          *(const uint4*)&tsi[row][col * 8];
    }
  }
}

__global__ __launch_bounds__(256) void kan_gemm(const float* __restrict__ xT,
                                                const u16* __restrict__ sil,
                                                const u16* __restrict__ Bt,
                                                float* __restrict__ C) {
  __shared__ __align__(16) u16 As[128 * 64];
  __shared__ __align__(16) u16 Bs[128 * 64];
  const int tid  = threadIdx.x;
  const int lane = tid & 63;
  const int w    = tid >> 6;
  const int wm   = w >> 1, wn = w & 1;
  const int q    = lane >> 4, m16 = lane & 15;
  const int gx = blockIdx.x, gy = blockIdx.y;

  f32x4 acc[4][4];
#pragma unroll
  for (int i = 0; i < 4; ++i)
#pragma unroll
    for (int j = 0; j < 4; ++j) acc[i][j] = (f32x4){0.f, 0.f, 0.f, 0.f};

  const int srow = lane >> 3;
  const int swzc = (lane & 7) ^ srow;
  const u16* gb0 = Bt + (size_t)(gx * 128) * KTOT + swzc * 8;
  const int r7 = m16 & 15 & 7;
  const int dgrp = tid >> 5;
  const int nh   = tid & 31;

  for (int kk = 0; kk < KTOT; kk += 64) {
#pragma unroll
    for (int i = 0; i < 4; ++i) {
      const int rg = w * 32 + i * 8;
      __builtin_amdgcn_global_load_lds((gptr_t)(gb0 + (size_t)(rg + srow) * KTOT + kk),
                                       (sptr_t)&Bs[rg * 64], 16, 0, 0);
    }
    if (kk < KSPL) {
      const int d = (kk >> 3) + dgrp;
      const float4 xv = *(const float4*)(xT + (size_t)d * NROWS + gy * 128 + nh * 4);
      const float xa[4] = {xv.x, xv.y, xv.z, xv.w};
#pragma unroll
      for (int r = 0; r < 4; ++r) {
        const int row = nh * 4 + r;
        const uint4 wv = basis_pack(xa[r]);
        *(uint4*)&As[row * 64 + ((dgrp ^ (row & 7)) * 8)] = wv;
      }
    } else {
      const int kb = kk - KSPL;
#pragma unroll
      for (int i = 0; i < 4; ++i) {
        const int rg = w * 32 + i * 8;
        __builtin_amdgcn_global_load_lds(
            (gptr_t)(sil + (size_t)(gy * 128 + rg + srow) * IN_DIM + kb + swzc * 8),
            (sptr_t)&As[rg * 64], 16, 0, 0);
      }
    }
    __syncthreads();
#pragma unroll
    for (int ks = 0; ks < 64; ks += 32) {
      const int pc = ((ks >> 3) + q) ^ r7;
      bf16x8 af[4], bf[4];
#pragma unroll
      for (int mt = 0; mt < 4; ++mt)
        af[mt] = *(const bf16x8*)&As[(wm * 64 + mt * 16 + m16) * 64 + pc * 8];
#pragma unroll
      for (int nt = 0; nt < 4; ++nt)
        bf[nt] = *(const bf16x8*)&Bs[(wn * 64 + nt * 16 + m16) * 64 + pc * 8];
#pragma unroll
      for (int mt = 0; mt < 4; ++mt)
#pragma unroll
        for (int nt = 0; nt < 4; ++nt)
          acc[mt][nt] = __builtin_amdgcn_mfma_f32_16x16x32_bf16(af[mt], bf[nt],
                                                                acc[mt][nt], 0, 0, 0);
    }
    __syncthreads();
  }

#pragma unroll
  for (int mt = 0; mt < 4; ++mt) {
    const int row0 = gy * 128 + wm * 64 + mt * 16 + q * 4;
#pragma unroll
    for (int nt = 0; nt < 4; ++nt) {
      const int col = gx * 128 + wn * 64 + nt * 16 + m16;
#pragma unroll
      for (int r = 0; r < 4; ++r)
        C[(size_t)(row0 + r) * OUT_DIM + col] = acc[mt][nt][r];
    }
  }
}

// ---------------------------------------------------------------------------
// Fallback (workspace too small): fused direct fp32 computation.
// ---------------------------------------------------------------------------
__global__ __launch_bounds__(256) void kan_fallback(const float* __restrict__ x,
                                                    const float* __restrict__ grid,
                                                    const float* __restrict__ coef,
                                                    const float* __restrict__ scale_base,
                                                    const float* __restrict__ scale_sp,
                                                    float* __restrict__ out) {
  __shared__ float bs[IN_DIM * 9];  // 36 KB
  const int n = blockIdx.x;
  const int t = threadIdx.x;
#pragma unroll
  for (int dd = 0; dd < IN_DIM / 256; ++dd) {
    const int d = t + dd * 256;
    const float xv = x[(size_t)n * IN_DIM + d];
    float tt = (xv + 1.0f) * 2.5f;
    float jf = floorf(tt);
    jf = fminf(fmaxf(jf, 0.0f), 4.0f);
    const float u = tt - jf;
    const int j = (int)jf;
    const float um = 1.0f - u;
    const float u2 = u * u, u3 = u2 * u;
    float* r = &bs[d * 9];
#pragma unroll
    for (int g = 0; g < NB; ++g) r[g] = 0.0f;
    r[j]     = um * um * um * (1.0f / 6.0f);
    r[j + 1] = (3.0f * u3 - 6.0f * u2 + 4.0f) * (1.0f / 6.0f);
    r[j + 2] = (-3.0f * u3 + 3.0f * u2 + 3.0f * u + 1.0f) * (1.0f / 6.0f);
    r[j + 3] = u3 * (1.0f / 6.0f);
    r[8]     = xv * rcp_fast(1.0f + __expf(-xv));
  }
  __syncthreads();
  const int o = blockIdx.y * 256 + t;
  float acc = 0.0f;
  for (int d = 0; d < IN_DIM; ++d) {
    const size_t doff = (size_t)d * OUT_DIM + o;
    const float4* cp = (const float4*)(coef + doff * 8);
    float4 c0 = cp[0], c1 = cp[1];
    const float* b = &bs[d * 9];
    float s = b[0] * c0.x + b[1] * c0.y + b[2] * c0.z + b[3] * c0.w +
              b[4] * c1.x + b[5] * c1.y + b[6] * c1.z + b[7] * c1.w;
    acc += s * scale_sp[doff] + b[8] * scale_base[doff];
  }
  out[(size_t)n * OUT_DIM + o] = acc;
}

extern "C" void kernel_launch(void* const* d_in, const int* in_sizes, int n_in,
                              void* d_out, int out_size, void* d_ws, size_t ws_size,
                              hipStream_t stream) {
  const float* x  = (const float*)d_in[0];  // (4,2048,1024)
  const float* gr = (const float*)d_in[1];  // (1024,12)  (uniform; unused in fast path)
  const float* cf = (const float*)d_in[2];  // (1024,2048,8)
  const float* sb = (const float*)d_in[3];  // (1024,2048)
  const float* sp = (const float*)d_in[4];  // (1024,2048)
  float* out = (float*)d_out;               // (4,2048,2048)

  const size_t act_bytes = (size_t)NROWS * KTOT * sizeof(u16);    // 151 MB
  const size_t wt_bytes  = (size_t)OUT_DIM * KTOT * sizeof(u16);  // 37.7 MB
  const size_t need1 = act_bytes + wt_bytes;                      // ~189 MB

  const size_t xT_bytes  = (size_t)IN_DIM * NROWS * sizeof(float);  // 33.5 MB
  const size_t sil_bytes = (size_t)NROWS * IN_DIM * sizeof(u16);    // 16.8 MB
  const size_t need2 = xT_bytes + sil_bytes + wt_bytes;             // ~88 MB

  if (ws_size >= need1) {
    u16* act = (u16*)d_ws;
    u16* wt  = (u16*)((char*)d_ws + act_bytes);
    kan_prep2<<<dim3(ACT_BLOCKS + WT_BLOCKS), dim3(256), 0, stream>>>(
        x, cf, sb, sp, act, wt);
    kan_gemm2<<<dim3(256), dim3(512), 0, stream>>>(act, wt, out);
  } else if (ws_size >= need2) {
    float* xT = (float*)d_ws;
    u16* sil  = (u16*)((char*)d_ws + xT_bytes);
    u16* wt   = (u16*)((char*)d_ws + xT_bytes + sil_bytes);
    kan_prep<<<dim3(TR_BLOCKS + WT_BLOCKS), dim3(256), 0, stream>>>(
        x, cf, sb, sp, xT, sil, wt);
    kan_gemm<<<dim3(OUT_DIM / 128, NROWS / 128), dim3(256), 0, stream>>>(
        xT, sil, wt, out);
  } else {
    kan_fallback<<<dim3(NROWS, OUT_DIM / 256), dim3(256), 0, stream>>>(x, gr, cf, sb, sp, out);
  }
}

// Round 5
// 461.134 us; speedup vs baseline: 1.1007x; 1.1007x over previous
//
#include <hip/hip_runtime.h>
#include <hip/hip_bf16.h>
#include <cstdint>

typedef unsigned short u16;
typedef __bf16 bf16x8 __attribute__((ext_vector_type(8)));
typedef float  f32x4  __attribute__((ext_vector_type(4)));

typedef const __attribute__((address_space(1))) void* gptr_t;
typedef __attribute__((address_space(3))) void*       sptr_t;

#define IN_DIM  1024
#define OUT_DIM 2048
#define NROWS   8192            // 4*2048 samples
#define NB      8               // GRID + K   (basis functions per d)
#define KTOT    (IN_DIM * 9)    // 9216: k<8192 -> spline d*8+g ; k>=8192 -> silu d
#define KSPL    (IN_DIM * 8)    // 8192

#define WT_O 16                 // wt transpose tile: 16 o x 64 d
#define WT_D 64
#define TR_BLOCKS ((NROWS / 64) * (IN_DIM / 64))        // 2048 x-transpose blocks (tier-2)
#define WT_BLOCKS ((OUT_DIM / WT_O) * (IN_DIM / WT_D))  // 2048 wt blocks
#define ACT_BLOCKS ((NROWS / 64) * (IN_DIM / 64))       // 2048 act-build blocks (tier-1)

// Tier-1 GEMM geometry: 256x256 tile, BK=32, 4-deep K-tile pipeline.
#define BK 32
#define TILE_U16 (256 * BK)     // 8192 u16 = 16 KB per K-tile buffer (per matrix)
#define NKT (KTOT / BK)         // 288

__device__ __forceinline__ float rcp_fast(float v) { return __builtin_amdgcn_rcpf(v); }

// fp32 -> bf16 round-to-nearest-even bit pattern (finite inputs only)
__device__ __forceinline__ u16 f2b(float v) {
  uint32_t u = __float_as_uint(v);
  uint32_t r = (u + 0x7FFFu + ((u >> 16) & 1u)) >> 16;
  return (u16)r;
}

// pack two fp32 -> packed bf16x2 (a in low half), RNE
__device__ __forceinline__ uint32_t pkbf(float a, float b) {
  return (uint32_t)f2b(a) | ((uint32_t)f2b(b) << 16);
}

// Uniform-knot cardinal cubic: 8 spline channels for one x, packed as 4x u32
// (bf16 pairs, channel g ascending). j=floor((x+1)*2.5) in [0,4], u=frac;
// nonzero channels j..j+3 = {(1-u)^3, 3u^3-6u^2+4, -3u^3+3u^2+3u+1, u^3}/6.
__device__ __forceinline__ uint4 basis_pack(float xval) {
  float tt = (xval + 1.0f) * 2.5f;
  float jf = floorf(tt);
  jf = fminf(fmaxf(jf, 0.0f), 4.0f);
  const float u = tt - jf;
  const int j = (int)jf;
  const float um = 1.0f - u;
  const float u2 = u * u, u3 = u2 * u;
  const float b0 = um * um * um * (1.0f / 6.0f);
  const float b1 = (3.0f * u3 - 6.0f * u2 + 4.0f) * (1.0f / 6.0f);
  const float b2 = (-3.0f * u3 + 3.0f * u2 + 3.0f * u + 1.0f) * (1.0f / 6.0f);
  const float b3 = u3 * (1.0f / 6.0f);
  const uint32_t e01 = pkbf(b0, b1), e23 = pkbf(b2, b3);
  const uint32_t o0 = e01 << 16;                      // (0, h0)
  const uint32_t o12 = (e01 >> 16) | (e23 << 16);     // (h1, h2)
  const uint32_t o3 = e23 >> 16;                      // (h3, 0)
  const int odd = j & 1, m = j >> 1;
  const uint32_t a0 = odd ? o0 : e01;
  const uint32_t a1 = odd ? o12 : e23;
  const uint32_t a2 = odd ? o3 : 0u;
  uint4 wv;
  wv.x = (m == 0) ? a0 : 0u;
  wv.y = (m == 1) ? a0 : ((m == 0) ? a1 : 0u);
  wv.z = (m == 2) ? a0 : ((m == 1) ? a1 : ((m == 0) ? a2 : 0u));
  wv.w = (m == 2) ? a1 : ((m == 1) ? a2 : 0u);
  return wv;
}

// ---------------------------------------------------------------------------
// TIER-1 prep: blocks [0,ACT_BLOCKS) materialize act[n][k] bf16
// (k<8192: spline basis d*8+g ; k>=8192: silu(x[n][d])). Blocks
// [ACT_BLOCKS,+WT_BLOCKS) build Wt[o][k] (coef*scale_sp / scale_base) bf16.
// (Unchanged; ~140us, will surface in top-5 counters once gemm < 290us.)
// ---------------------------------------------------------------------------
__global__ __launch_bounds__(256) void kan_prep2(const float* __restrict__ x,
                                                 const float* __restrict__ coef,
                                                 const float* __restrict__ scale_base,
                                                 const float* __restrict__ scale_sp,
                                                 u16* __restrict__ act,
                                                 u16* __restrict__ wt) {
  const int t = threadIdx.x;

  if (blockIdx.x < ACT_BLOCKS) {
    // ---- act tile: 64 n x 64 d ----
    __shared__ __align__(16) u16 st[64][72];   // silu staging (pad 72 breaks banks)
    const int bi = blockIdx.x;
    const int n0 = (bi & 127) * 64;
    const int d0 = (bi >> 7) * 64;
    const int dl = t & 63, r0 = t >> 6;        // r0 in 0..3
#pragma unroll
    for (int i = 0; i < 16; ++i) {
      const int r = r0 + i * 4;
      const float v = x[(size_t)(n0 + r) * IN_DIM + d0 + dl];
      *(uint4*)&act[(size_t)(n0 + r) * KTOT + (size_t)(d0 + dl) * 8] = basis_pack(v);
      st[r][dl] = f2b(v * rcp_fast(1.0f + __expf(-v)));
    }
    __syncthreads();
#pragma unroll
    for (int j = 0; j < 2; ++j) {
      const int idx = t + j * 256;
      const int r = idx >> 3, c8 = idx & 7;
      *(uint4*)&act[(size_t)(n0 + r) * KTOT + KSPL + d0 + c8 * 8] =
          *(const uint4*)&st[r][c8 * 8];
    }
  } else {
    // ---- Wt path: 16o x 64d transpose tile ----
    __shared__ __align__(16) u16 tsp[WT_O][WT_D * 8 + 8];
    __shared__ __align__(16) u16 tsi[WT_O][WT_D + 8];
    const int bi = blockIdx.x - ACT_BLOCKS;
    const int o0 = (bi % (OUT_DIM / WT_O)) * WT_O;
    const int d0 = (bi / (OUT_DIM / WT_O)) * WT_D;
    const int ol = t & (WT_O - 1), dl0 = t >> 4;  // dl0 in 0..15
#pragma unroll
    for (int rep = 0; rep < WT_D / 16; ++rep) {
      const int dl = rep * 16 + dl0;
      const int d = d0 + dl, o = o0 + ol;
      const size_t doff = (size_t)d * OUT_DIM + o;
      const float ssp = scale_sp[doff];
      const float sbv = scale_base[doff];
      const float4* cp = (const float4*)(coef + doff * 8);
      float4 c0 = cp[0], c1 = cp[1];
      uint4 val;
      val.x = pkbf(c0.x * ssp, c0.y * ssp);
      val.y = pkbf(c0.z * ssp, c0.w * ssp);
      val.z = pkbf(c1.x * ssp, c1.y * ssp);
      val.w = pkbf(c1.z * ssp, c1.w * ssp);
      *(uint4*)&tsp[ol][dl * 8] = val;
      tsi[ol][dl] = f2b(sbv);
    }
    __syncthreads();
    for (int i = t; i < WT_O * 64; i += 256) {
      const int row = i >> 6, col = i & 63;
      *(uint4*)(wt + (size_t)(o0 + row) * KTOT + (size_t)(d0 + col) * 8) =
          *(const uint4*)&tsp[row][col * 8];
    }
    if (t < WT_O * 8) {
      const int row = t >> 3, col = t & 7;
      *(uint4*)(wt + (size_t)(o0 + row) * KTOT + KSPL + d0 + col * 8) =
          *(const uint4*)&tsi[row][col * 8];
    }
  }
}

// ---------------------------------------------------------------------------
// TIER-1 GEMM: C[8192x2048] = act * Wt^T, pure bf16 MFMA GEMM.
// R3 structure (294us, best known) + sched_group_barrier interleave pin.
// R3 PMC showed MFMA pipe (46.6%) and LDS pipe (~43%) running back-to-back
// serially: the compiler sinks the 12 independent ds_reads after the 32
// MFMAs, so both waves/SIMD burst LDS only after their MFMA burst. The SGB
// pattern {4 MFMA, 1 DS_READ}x8 + {DS_READ x4} pins the EMITTED order to the
// source interleave (no renaming -> no VGPR growth past the 256-reg cliff),
// letting the LDS unit drain the 12 reads during the 1242-cyc MFMA stream.
// Ledger (unchanged from R3): stage distance 4; region T reads buf (T+1)&3,
// stages tile T+4 into buf T&3 (last read in region T-1, lgkm(0)-drained);
// vmcnt(8) retires tile T+2's loads; tail 4 -> 0.
// ---------------------------------------------------------------------------
__global__ __launch_bounds__(512, 2) void kan_gemm2(const u16* __restrict__ act,
                                                    const u16* __restrict__ Bt,
                                                    float* __restrict__ C) {
  __shared__ __align__(16) u16 As[4 * TILE_U16];  // 64 KB
  __shared__ __align__(16) u16 Bs[4 * TILE_U16];  // 64 KB
  const int tid  = threadIdx.x;
  const int lane = tid & 63;
  const int w    = tid >> 6;            // 0..7
  const int wm   = w >> 2, wn = w & 3;  // 2 x 4 wave grid
  const int q    = lane >> 4, m16 = lane & 15;

  // Bijective XCD swizzle: 256 wgs = 8 XCDs x 32; gx fastest so the 8 blocks
  // sharing an A row-panel land on one XCD's L2.
  const int bid = (blockIdx.x & 7) * 32 + (blockIdx.x >> 3);
  const int gx = bid & 7;    // o-tile   (N/256 = 8)
  const int gy = bid >> 3;   // row-tile (M/256 = 32)

  f32x4 acc[8][4];
#pragma unroll
  for (int i = 0; i < 8; ++i)
#pragma unroll
    for (int j = 0; j < 4; ++j) acc[i][j] = (f32x4){0.f, 0.f, 0.f, 0.f};

  // Staging: per K-tile each matrix is 256x32 bf16 = 16 KB = 16 wave-issues;
  // wave w covers rows [w*32, w*32+32) via 2 issues of 16 rows (1 KB each).
  // Lane l -> row w*32 + i*16 + (l>>2), phys chunk l&3; source logical chunk
  // = (l&3) ^ ((row>>1)&3) = (l&3) ^ ((l>>3)&3)  (w,i terms vanish mod 4).
  const int rA  = lane >> 2;
  const int csw = ((lane & 3) ^ ((lane >> 3) & 3)) * 8;  // u16 offset
  const u16* gA = act + (size_t)(gy * 256 + w * 32 + rA) * KTOT + csw;
  const u16* gB = Bt  + (size_t)(gx * 256 + w * 32 + rA) * KTOT + csw;
  const int ldsw = w * 1024;  // u16 offset of this wave's 32-row segment

#define STAGE(T)                                                               \
  do {                                                                         \
    const int _buf = (T) & 3;                                                  \
    const size_t _k0 = (size_t)(T) * BK;                                       \
    const u16* _ga = gA + _k0;                                                 \
    const u16* _gb = gB + _k0;                                                 \
    u16* _la = &As[_buf * TILE_U16 + ldsw];                                    \
    u16* _lb = &Bs[_buf * TILE_U16 + ldsw];                                    \
    __builtin_amdgcn_global_load_lds((gptr_t)_ga, (sptr_t)_la, 16, 0, 0);      \
    __builtin_amdgcn_global_load_lds((gptr_t)(_ga + (size_t)16 * KTOT),        \
                                     (sptr_t)(_la + 512), 16, 0, 0);           \
    __builtin_amdgcn_global_load_lds((gptr_t)_gb, (sptr_t)_lb, 16, 0, 0);      \
    __builtin_amdgcn_global_load_lds((gptr_t)(_gb + (size_t)16 * KTOT),        \
                                     (sptr_t)(_lb + 512), 16, 0, 0);           \
  } while (0)

  // Fragment reads: row base (wm*128 | wn*64) + frag*16 + m16, phys chunk
  // q ^ ((m16>>1)&3) (frag-independent since frag*16 is 0 mod 4 after >>1).
  const int px8 = (q ^ ((m16 >> 1) & 3)) * 8;
  const int aoff = (wm * 128 + m16) * 32 + px8;
  const int boff = (wn * 64 + m16) * 32 + px8;

  bf16x8 fa[8], fb[4];  // current-tile fragments (all indexing fully unrolled)

  // Region T: MFMA with fragments of tile T (in regs) while reloading
  // fragments of tile T+1 from LDS buf (T+1)&3 and staging tile T+4.
  // SGB masks (m137-verified on gfx950): MFMA=0x008, DS_READ=0x100.
#define REGION(T, DOREAD, DOSTAGE, VM)                                         \
  do {                                                                         \
    const u16* _An = &As[(((T) + 1) & 3) * TILE_U16 + aoff];                   \
    const u16* _Bn = &Bs[(((T) + 1) & 3) * TILE_U16 + boff];                   \
    if (DOSTAGE) STAGE((T) + 4);                                               \
    __builtin_amdgcn_s_setprio(1);                                             \
    _Pragma("unroll") for (int mt = 0; mt < 8; ++mt) {                         \
      _Pragma("unroll") for (int nt = 0; nt < 4; ++nt)                         \
        acc[mt][nt] = __builtin_amdgcn_mfma_f32_16x16x32_bf16(                 \
            fa[mt], fb[nt], acc[mt][nt], 0, 0, 0);                             \
      if (DOREAD) fa[mt] = *(const bf16x8*)&_An[mt * 512];                     \
    }                                                                          \
    if (DOREAD) {                                                              \
      _Pragma("unroll") for (int nt = 0; nt < 4; ++nt)                         \
        fb[nt] = *(const bf16x8*)&_Bn[nt * 512];                               \
    }                                                                          \
    __builtin_amdgcn_s_setprio(0);                                             \
    if (DOREAD) {                                                              \
      _Pragma("unroll") for (int g = 0; g < 8; ++g) {                          \
        __builtin_amdgcn_sched_group_barrier(0x008, 4, 0);                     \
        __builtin_amdgcn_sched_group_barrier(0x100, 1, 0);                     \
      }                                                                        \
      __builtin_amdgcn_sched_group_barrier(0x100, 4, 0);                       \
    }                                                                          \
    asm volatile("s_waitcnt vmcnt(" #VM ")" ::: "memory");                     \
    asm volatile("s_waitcnt lgkmcnt(0)" ::: "memory");                         \
    __builtin_amdgcn_s_barrier();                                              \
  } while (0)

  // Prologue: fill 4 K-tiles (16 loads/thread); wait until tiles 0,1 landed
  // (vmcnt(8): newest 8 = tiles 2,3); then preload tile-0 fragments.
  STAGE(0);
  STAGE(1);
  STAGE(2);
  STAGE(3);
  asm volatile("s_waitcnt vmcnt(8)" ::: "memory");
  __builtin_amdgcn_s_barrier();
  {
    const u16* _A0 = &As[aoff];
    const u16* _B0 = &Bs[boff];
#pragma unroll
    for (int nt = 0; nt < 4; ++nt) fb[nt] = *(const bf16x8*)&_B0[nt * 512];
#pragma unroll
    for (int mt = 0; mt < 8; ++mt) fa[mt] = *(const bf16x8*)&_A0[mt * 512];
  }

  // Main: regions 0..283 stage tiles 4..287; vmcnt(8) -> tile t+2 landed.
  for (int tb = 0; tb < 71; ++tb) {
#pragma unroll
    for (int j = 0; j < 4; ++j) {
      REGION(tb * 4 + j, true, true, 8);
    }
  }
  // Tail: no more staging; drain 4 -> 0.
  REGION(284, true, false, 4);
  REGION(285, true, false, 0);
  REGION(286, true, false, 0);
  // Region 287: consume-only (fragments of tile 287 already in regs).
  __builtin_amdgcn_s_setprio(1);
#pragma unroll
  for (int mt = 0; mt < 8; ++mt)
#pragma unroll
    for (int nt = 0; nt < 4; ++nt)
      acc[mt][nt] = __builtin_amdgcn_mfma_f32_16x16x32_bf16(fa[mt], fb[nt],
                                                            acc[mt][nt], 0, 0, 0);
  __builtin_amdgcn_s_setprio(0);

#undef REGION
#undef STAGE

  // Epilogue: C/D layout col = lane&15, row = (lane>>4)*4 + reg (m89-verified)
  const int row_base = gy * 256 + wm * 128 + q * 4;
  const int col_base = gx * 256 + wn * 64 + m16;
#pragma unroll
  for (int mt = 0; mt < 8; ++mt) {
#pragma unroll
    for (int nt = 0; nt < 4; ++nt) {
      const int r0 = row_base + mt * 16;
      const int c  = col_base + nt * 16;
#pragma unroll
      for (int r = 0; r < 4; ++r)
        C[(size_t)(r0 + r) * OUT_DIM + c] = acc[mt][nt][r];
    }
  }
}

// ---------------------------------------------------------------------------
// TIER-2 (previous session's best, ws >= 88MB): on-the-fly A, 128^2 tile.
// ---------------------------------------------------------------------------
__global__ __launch_bounds__(256) void kan_prep(const float* __restrict__ x,
                                                const float* __restrict__ coef,
                                                const float* __restrict__ scale_base,
                                                const float* __restrict__ scale_sp,
                                                float* __restrict__ xT,
                                                u16* __restrict__ sil,
                                                u16* __restrict__ wt) {
  const int t = threadIdx.x;

  if (blockIdx.x < TR_BLOCKS) {
    __shared__ float tile[64][65];
    const int bi = blockIdx.x;
    const int n0 = (bi & 127) * 64;
    const int d0 = (bi >> 7) * 64;
    const int col = t & 63, rbase = t >> 6;
#pragma unroll
    for (int i = 0; i < 16; ++i) {
      const int r = rbase + i * 4;
      const float v = x[(size_t)(n0 + r) * IN_DIM + d0 + col];
      tile[r][col] = v;
      sil[(size_t)(n0 + r) * IN_DIM + d0 + col] =
          f2b(v * rcp_fast(1.0f + __expf(-v)));
    }
    __syncthreads();
#pragma unroll
    for (int i = 0; i < 16; ++i) {
      const int dd = rbase + i * 4;
      xT[(size_t)(d0 + dd) * NROWS + n0 + col] = tile[col][dd];
    }
  } else {
    __shared__ __align__(16) u16 tsp[WT_O][WT_D * 8 + 8];
    __shared__ __align__(16) u16 tsi[WT_O][WT_D + 8];
    const int bi = blockIdx.x - TR_BLOCKS;
    const int o0 = (bi % (OUT_DIM / WT_O)) * WT_O;
    const int d0 = (bi / (OUT_DIM / WT_O)) * WT_D;
    const int ol = t & (WT_O - 1), dl0 = t >> 4;
#pragma unroll
    for (int rep = 0; rep < WT_D / 16; ++rep) {
      const int dl = rep * 16 + dl0;
      const int d = d0 + dl, o = o0 + ol;
      const size_t doff = (size_t)d * OUT_DIM + o;
      const float ssp = scale_sp[doff];
      const float sbv = scale_base[doff];
      const float4* cp = (const float4*)(coef + doff * 8);
      float4 c0 = cp[0], c1 = cp[1];
      uint4 val;
      val.x = pkbf(c0.x * ssp, c0.y * ssp);
      val.y = pkbf(c0.z * ssp, c0.w * ssp);
      val.z = pkbf(c1.x * ssp, c1.y * ssp);
      val.w = pkbf(c1.z * ssp, c1.w * ssp);
      *(uint4*)&tsp[ol][dl * 8] = val;
      tsi[ol][dl] = f2b(sbv);
    }
    __syncthreads();
    for (int i = t; i < WT_O * 64; i += 256) {
      const int row = i >> 6, col = i & 63;
      *(uint4*)(wt + (size_t)(o0 + row) * KTOT + (size_t)(d0 + col) * 8) =
          *(const uint4*)&tsp[row][col * 8];
    }
    if (t < WT_O * 8) {
      const int row = t >> 3, col = t & 7;
      *(uint4*)(wt + (size_t)(o0 + row) * KTOT + KSPL + d0 + col * 8) =
          *(const uint4*)&tsi[row][col * 8];
    }
  }
}

__global__ __launch_bounds__(256) void kan_gemm(const float* __restrict__ xT,
                                                const u16* __restrict__ sil,
                                                const u16* __restrict__ Bt,
                                                float* __restrict__ C) {
  __shared__ __align__(16) u16 As[128 * 64];
  __shared__ __align__(16) u16 Bs[128 * 64];
  const int tid  = threadIdx.x;
  const int lane = tid & 63;
  const int w    = tid >> 6;
  const int wm   = w >> 1, wn = w & 1;
  const int q    = lane >> 4, m16 = lane & 15;
  const int gx = blockIdx.x, gy = blockIdx.y;

  f32x4 acc[4][4];
#pragma unroll
  for (int i = 0; i < 4; ++i)
#pragma unroll
    for (int j = 0; j < 4; ++j) acc[i][j] = (f32x4){0.f, 0.f, 0.f, 0.f};

  const int srow = lane >> 3;
  const int swzc = (lane & 7) ^ srow;
  const u16* gb0 = Bt + (size_t)(gx * 128) * KTOT + swzc * 8;
  const int r7 = m16 & 15 & 7;
  const int dgrp = tid >> 5;
  const int nh   = tid & 31;

  for (int kk = 0; kk < KTOT; kk += 64) {
#pragma unroll
    for (int i = 0; i < 4; ++i) {
      const int rg = w * 32 + i * 8;
      __builtin_amdgcn_global_load_lds((gptr_t)(gb0 + (size_t)(rg + srow) * KTOT + kk),
                                       (sptr_t)&Bs[rg * 64], 16, 0, 0);
    }
    if (kk < KSPL) {
      const int d = (kk >> 3) + dgrp;
      const float4 xv = *(const float4*)(xT + (size_t)d * NROWS + gy * 128 + nh * 4);
      const float xa[4] = {xv.x, xv.y, xv.z, xv.w};
#pragma unroll
      for (int r = 0; r < 4; ++r) {
        const int row = nh * 4 + r;
        const uint4 wv = basis_pack(xa[r]);
        *(uint4*)&As[row * 64 + ((dgrp ^ (row & 7)) * 8)] = wv;
      }
    } else {
      const int kb = kk - KSPL;
#pragma unroll
      for (int i = 0; i < 4; ++i) {
        const int rg = w * 32 + i * 8;
        __builtin_amdgcn_global_load_lds(
            (gptr_t)(sil + (size_t)(gy * 128 + rg + srow) * IN_DIM + kb + swzc * 8),
            (sptr_t)&As[rg * 64], 16, 0, 0);
      }
    }
    __syncthreads();
#pragma unroll
    for (int ks = 0; ks < 64; ks += 32) {
      const int pc = ((ks >> 3) + q) ^ r7;
      bf16x8 af[4], bf[4];
#pragma unroll
      for (int mt = 0; mt < 4; ++mt)
        af[mt] = *(const bf16x8*)&As[(wm * 64 + mt * 16 + m16) * 64 + pc * 8];
#pragma unroll
      for (int nt = 0; nt < 4; ++nt)
        bf[nt] = *(const bf16x8*)&Bs[(wn * 64 + nt * 16 + m16) * 64 + pc * 8];
#pragma unroll
      for (int mt = 0; mt < 4; ++mt)
#pragma unroll
        for (int nt = 0; nt < 4; ++nt)
          acc[mt][nt] = __builtin_amdgcn_mfma_f32_16x16x32_bf16(af[mt], bf[nt],
                                                                acc[mt][nt], 0, 0, 0);
    }
    __syncthreads();
  }

#pragma unroll
  for (int mt = 0; mt < 4; ++mt) {
    const int row0 = gy * 128 + wm * 64 + mt * 16 + q * 4;
#pragma unroll
    for (int nt = 0; nt < 4; ++nt) {
      const int col = gx * 128 + wn * 64 + nt * 16 + m16;
#pragma unroll
      for (int r = 0; r < 4; ++r)
        C[(size_t)(row0 + r) * OUT_DIM + col] = acc[mt][nt][r];
    }
  }
}

// ---------------------------------------------------------------------------
// Fallback (workspace too small): fused direct fp32 computation.
// ---------------------------------------------------------------------------
__global__ __launch_bounds__(256) void kan_fallback(const float* __restrict__ x,
                                                    const float* __restrict__ grid,
                                                    const float* __restrict__ coef,
                                                    const float* __restrict__ scale_base,
                                                    const float* __restrict__ scale_sp,
                                                    float* __restrict__ out) {
  __shared__ float bs[IN_DIM * 9];  // 36 KB
  const int n = blockIdx.x;
  const int t = threadIdx.x;
#pragma unroll
  for (int dd = 0; dd < IN_DIM / 256; ++dd) {
    const int d = t + dd * 256;
    const float xv = x[(size_t)n * IN_DIM + d];
    float tt = (xv + 1.0f) * 2.5f;
    float jf = floorf(tt);
    jf = fminf(fmaxf(jf, 0.0f), 4.0f);
    const float u = tt - jf;
    const int j = (int)jf;
    const float um = 1.0f - u;
    const float u2 = u * u, u3 = u2 * u;
    float* r = &bs[d * 9];
#pragma unroll
    for (int g = 0; g < NB; ++g) r[g] = 0.0f;
    r[j]     = um * um * um * (1.0f / 6.0f);
    r[j + 1] = (3.0f * u3 - 6.0f * u2 + 4.0f) * (1.0f / 6.0f);
    r[j + 2] = (-3.0f * u3 + 3.0f * u2 + 3.0f * u + 1.0f) * (1.0f / 6.0f);
    r[j + 3] = u3 * (1.0f / 6.0f);
    r[8]     = xv * rcp_fast(1.0f + __expf(-xv));
  }
  __syncthreads();
  const int o = blockIdx.y * 256 + t;
  float acc = 0.0f;
  for (int d = 0; d < IN_DIM; ++d) {
    const size_t doff = (size_t)d * OUT_DIM + o;
    const float4* cp = (const float4*)(coef + doff * 8);
    float4 c0 = cp[0], c1 = cp[1];
    const float* b = &bs[d * 9];
    float s = b[0] * c0.x + b[1] * c0.y + b[2] * c0.z + b[3] * c0.w +
              b[4] * c1.x + b[5] * c1.y + b[6] * c1.z + b[7] * c1.w;
    acc += s * scale_sp[doff] + b[8] * scale_base[doff];
  }
  out[(size_t)n * OUT_DIM + o] = acc;
}

extern "C" void kernel_launch(void* const* d_in, const int* in_sizes, int n_in,
                              void* d_out, int out_size, void* d_ws, size_t ws_size,
                              hipStream_t stream) {
  const float* x  = (const float*)d_in[0];  // (4,2048,1024)
  const float* gr = (const float*)d_in[1];  // (1024,12)  (uniform; unused in fast path)
  const float* cf = (const float*)d_in[2];  // (1024,2048,8)
  const float* sb = (const float*)d_in[3];  // (1024,2048)
  const float* sp = (const float*)d_in[4];  // (1024,2048)
  float* out = (float*)d_out;               // (4,2048,2048)

  const size_t act_bytes = (size_t)NROWS * KTOT * sizeof(u16);    // 151 MB
  const size_t wt_bytes  = (size_t)OUT_DIM * KTOT * sizeof(u16);  // 37.7 MB
  const size_t need1 = act_bytes + wt_bytes;                      // ~189 MB

  const size_t xT_bytes  = (size_t)IN_DIM * NROWS * sizeof(float);  // 33.5 MB
  const size_t sil_bytes = (size_t)NROWS * IN_DIM * sizeof(u16);    // 16.8 MB
  const size_t need2 = xT_bytes + sil_bytes + wt_bytes;             // ~88 MB

  if (ws_size >= need1) {
    u16* act = (u16*)d_ws;
    u16* wt  = (u16*)((char*)d_ws + act_bytes);
    kan_prep2<<<dim3(ACT_BLOCKS + WT_BLOCKS), dim3(256), 0, stream>>>(
        x, cf, sb, sp, act, wt);
    kan_gemm2<<<dim3(256), dim3(512), 0, stream>>>(act, wt, out);
  } else if (ws_size >= need2) {
    float* xT = (float*)d_ws;
    u16* sil  = (u16*)((char*)d_ws + xT_bytes);
    u16* wt   = (u16*)((char*)d_ws + xT_bytes + sil_bytes);
    kan_prep<<<dim3(TR_BLOCKS + WT_BLOCKS), dim3(256), 0, stream>>>(
        x, cf, sb, sp, xT, sil, wt);
    kan_gemm<<<dim3(OUT_DIM / 128, NROWS / 128), dim3(256), 0, stream>>>(
        xT, sil, wt, out);
  } else {
    kan_fallback<<<dim3(NROWS, OUT_DIM / 256), dim3(256), 0, stream>>>(x, gr, cf, sb, sp, out);
  }
}

// Round 6
// 441.277 us; speedup vs baseline: 1.1502x; 1.0450x over previous
//
#include <hip/hip_runtime.h>
#include <hip/hip_bf16.h>
#include <cstdint>

typedef unsigned short u16;
typedef __bf16 bf16x8 __attribute__((ext_vector_type(8)));
typedef float  f32x4  __attribute__((ext_vector_type(4)));

typedef const __attribute__((address_space(1))) void* gptr_t;
typedef __attribute__((address_space(3))) void*       sptr_t;

#define IN_DIM  1024
#define OUT_DIM 2048
#define NROWS   8192            // 4*2048 samples
#define NB      8               // GRID + K   (basis functions per d)
#define KTOT    (IN_DIM * 9)    // 9216: k<8192 -> spline d*8+g ; k>=8192 -> silu d
#define KSPL    (IN_DIM * 8)    // 8192

#define WT_O 16                 // wt transpose tile: 16 o x 64 d
#define WT_D 64
#define TR_BLOCKS ((NROWS / 64) * (IN_DIM / 64))        // 2048 x-transpose blocks (tier-2)
#define WT_BLOCKS ((OUT_DIM / WT_O) * (IN_DIM / WT_D))  // 2048 wt blocks
#define ACT2_BLOCKS ((NROWS / 64) * (IN_DIM / 32))      // 4096 act blocks (64n x 32d)

// Tier-1 GEMM geometry: 256x256 tile, BK=32, 4-deep K-tile pipeline.
#define BK 32
#define TILE_U16 (256 * BK)     // 8192 u16 = 16 KB per K-tile buffer (per matrix)
#define NKT (KTOT / BK)         // 288

__device__ __forceinline__ float rcp_fast(float v) { return __builtin_amdgcn_rcpf(v); }

// fp32 -> bf16 round-to-nearest-even bit pattern (finite inputs only)
__device__ __forceinline__ u16 f2b(float v) {
  uint32_t u = __float_as_uint(v);
  uint32_t r = (u + 0x7FFFu + ((u >> 16) & 1u)) >> 16;
  return (u16)r;
}

// pack two fp32 -> packed bf16x2 (a in low half), RNE
__device__ __forceinline__ uint32_t pkbf(float a, float b) {
  return (uint32_t)f2b(a) | ((uint32_t)f2b(b) << 16);
}

// Uniform-knot cardinal cubic: 8 spline channels for one x, packed as 4x u32
// (bf16 pairs, channel g ascending). j=floor((x+1)*2.5) in [0,4], u=frac;
// nonzero channels j..j+3 = {(1-u)^3, 3u^3-6u^2+4, -3u^3+3u^2+3u+1, u^3}/6.
__device__ __forceinline__ uint4 basis_pack(float xval) {
  float tt = (xval + 1.0f) * 2.5f;
  float jf = floorf(tt);
  jf = fminf(fmaxf(jf, 0.0f), 4.0f);
  const float u = tt - jf;
  const int j = (int)jf;
  const float um = 1.0f - u;
  const float u2 = u * u, u3 = u2 * u;
  const float b0 = um * um * um * (1.0f / 6.0f);
  const float b1 = (3.0f * u3 - 6.0f * u2 + 4.0f) * (1.0f / 6.0f);
  const float b2 = (-3.0f * u3 + 3.0f * u2 + 3.0f * u + 1.0f) * (1.0f / 6.0f);
  const float b3 = u3 * (1.0f / 6.0f);
  const uint32_t e01 = pkbf(b0, b1), e23 = pkbf(b2, b3);
  const uint32_t o0 = e01 << 16;                      // (0, h0)
  const uint32_t o12 = (e01 >> 16) | (e23 << 16);     // (h1, h2)
  const uint32_t o3 = e23 >> 16;                      // (h3, 0)
  const int odd = j & 1, m = j >> 1;
  const uint32_t a0 = odd ? o0 : e01;
  const uint32_t a1 = odd ? o12 : e23;
  const uint32_t a2 = odd ? o3 : 0u;
  uint4 wv;
  wv.x = (m == 0) ? a0 : 0u;
  wv.y = (m == 1) ? a0 : ((m == 0) ? a1 : 0u);
  wv.z = (m == 2) ? a0 : ((m == 1) ? a1 : ((m == 0) ? a2 : 0u));
  wv.w = (m == 2) ? a1 : ((m == 1) ? a2 : 0u);
  return wv;
}

// ---------------------------------------------------------------------------
// TIER-1 prep (rewritten): blocks [0,ACT2_BLOCKS) materialize act[n][k] bf16
// single-pass, NO LDS, NO __syncthreads: spline basis as 16B/lane coalesced
// uint4 stores; silu as 2B/lane stores (contiguous 128B/wave -> coalesced).
// 4096 blocks of 64n x 32d (8 row-iters/thread) for tail/latency hiding.
// Blocks [ACT2_BLOCKS,+WT_BLOCKS) build Wt[o][k] as before.
// Roofline: 323MB total traffic ~ 51us; previous structure measured ~150us.
// ---------------------------------------------------------------------------
__global__ __launch_bounds__(256) void kan_prep2(const float* __restrict__ x,
                                                 const float* __restrict__ coef,
                                                 const float* __restrict__ scale_base,
                                                 const float* __restrict__ scale_sp,
                                                 u16* __restrict__ act,
                                                 u16* __restrict__ wt) {
  const int t = threadIdx.x;

  if (blockIdx.x < ACT2_BLOCKS) {
    // ---- act tile: 64 n x 32 d, single pass ----
    const int bi = blockIdx.x;
    const int n0 = (bi & 127) * 64;
    const int d0 = (bi >> 7) * 32;
    const int dl = t & 31, r0 = t >> 5;        // r0 in 0..7
#pragma unroll
    for (int i = 0; i < 8; ++i) {
      const int r = r0 + i * 8;
      const size_t rowk = (size_t)(n0 + r) * KTOT;
      const float v = x[(size_t)(n0 + r) * IN_DIM + d0 + dl];
      *(uint4*)&act[rowk + (size_t)(d0 + dl) * 8] = basis_pack(v);
      act[rowk + KSPL + d0 + dl] = f2b(v * rcp_fast(1.0f + __expf(-v)));
    }
  } else {
    // ---- Wt path: 16o x 64d transpose tile ----
    __shared__ __align__(16) u16 tsp[WT_O][WT_D * 8 + 8];
    __shared__ __align__(16) u16 tsi[WT_O][WT_D + 8];
    const int bi = blockIdx.x - ACT2_BLOCKS;
    const int o0 = (bi % (OUT_DIM / WT_O)) * WT_O;
    const int d0 = (bi / (OUT_DIM / WT_O)) * WT_D;
    const int ol = t & (WT_O - 1), dl0 = t >> 4;  // dl0 in 0..15
#pragma unroll
    for (int rep = 0; rep < WT_D / 16; ++rep) {
      const int dl = rep * 16 + dl0;
      const int d = d0 + dl, o = o0 + ol;
      const size_t doff = (size_t)d * OUT_DIM + o;
      const float ssp = scale_sp[doff];
      const float sbv = scale_base[doff];
      const float4* cp = (const float4*)(coef + doff * 8);
      float4 c0 = cp[0], c1 = cp[1];
      uint4 val;
      val.x = pkbf(c0.x * ssp, c0.y * ssp);
      val.y = pkbf(c0.z * ssp, c0.w * ssp);
      val.z = pkbf(c1.x * ssp, c1.y * ssp);
      val.w = pkbf(c1.z * ssp, c1.w * ssp);
      *(uint4*)&tsp[ol][dl * 8] = val;
      tsi[ol][dl] = f2b(sbv);
    }
    __syncthreads();
    for (int i = t; i < WT_O * 64; i += 256) {
      const int row = i >> 6, col = i & 63;
      *(uint4*)(wt + (size_t)(o0 + row) * KTOT + (size_t)(d0 + col) * 8) =
          *(const uint4*)&tsp[row][col * 8];
    }
    if (t < WT_O * 8) {
      const int row = t >> 3, col = t & 7;
      *(uint4*)(wt + (size_t)(o0 + row) * KTOT + KSPL + d0 + col * 8) =
          *(const uint4*)&tsi[row][col * 8];
    }
  }
}

// ---------------------------------------------------------------------------
// TIER-1 GEMM: exact R3 structure (best measured: 294us, MfmaUtil 46.6%).
// R5's sched_group_barrier pin regressed (314us) -> removed. Rolling register
// fragment prefetch: region T's 32 MFMAs consume fragments loaded in region
// T-1; the 12 ds_read_b128 for tile T+1 interleave into the MFMA stream.
// Ledger: stage distance 4; region T reads buf (T+1)&3, stages tile T+4 into
// buf T&3; vmcnt(8) at region end -> tiles <=T+2 landed (covers next region's
// reads of T+1... T+2); lgkm(0)+barrier closes cross-wave WAR.
// ---------------------------------------------------------------------------
__global__ __launch_bounds__(512, 2) void kan_gemm2(const u16* __restrict__ act,
                                                    const u16* __restrict__ Bt,
                                                    float* __restrict__ C) {
  __shared__ __align__(16) u16 As[4 * TILE_U16];  // 64 KB
  __shared__ __align__(16) u16 Bs[4 * TILE_U16];  // 64 KB
  const int tid  = threadIdx.x;
  const int lane = tid & 63;
  const int w    = tid >> 6;            // 0..7
  const int wm   = w >> 2, wn = w & 3;  // 2 x 4 wave grid
  const int q    = lane >> 4, m16 = lane & 15;

  // Bijective XCD swizzle: 256 wgs = 8 XCDs x 32; gx fastest so the 8 blocks
  // sharing an A row-panel land on one XCD's L2.
  const int bid = (blockIdx.x & 7) * 32 + (blockIdx.x >> 3);
  const int gx = bid & 7;    // o-tile   (N/256 = 8)
  const int gy = bid >> 3;   // row-tile (M/256 = 32)

  f32x4 acc[8][4];
#pragma unroll
  for (int i = 0; i < 8; ++i)
#pragma unroll
    for (int j = 0; j < 4; ++j) acc[i][j] = (f32x4){0.f, 0.f, 0.f, 0.f};

  // Staging: per K-tile each matrix is 256x32 bf16 = 16 KB = 16 wave-issues;
  // wave w covers rows [w*32, w*32+32) via 2 issues of 16 rows (1 KB each).
  // Lane l -> row w*32 + i*16 + (l>>2), phys chunk l&3; source logical chunk
  // = (l&3) ^ ((row>>1)&3) = (l&3) ^ ((l>>3)&3)  (w,i terms vanish mod 4).
  const int rA  = lane >> 2;
  const int csw = ((lane & 3) ^ ((lane >> 3) & 3)) * 8;  // u16 offset
  const u16* gA = act + (size_t)(gy * 256 + w * 32 + rA) * KTOT + csw;
  const u16* gB = Bt  + (size_t)(gx * 256 + w * 32 + rA) * KTOT + csw;
  const int ldsw = w * 1024;  // u16 offset of this wave's 32-row segment

#define STAGE(T)                                                               \
  do {                                                                         \
    const int _buf = (T) & 3;                                                  \
    const size_t _k0 = (size_t)(T) * BK;                                       \
    const u16* _ga = gA + _k0;                                                 \
    const u16* _gb = gB + _k0;                                                 \
    u16* _la = &As[_buf * TILE_U16 + ldsw];                                    \
    u16* _lb = &Bs[_buf * TILE_U16 + ldsw];                                    \
    __builtin_amdgcn_global_load_lds((gptr_t)_ga, (sptr_t)_la, 16, 0, 0);      \
    __builtin_amdgcn_global_load_lds((gptr_t)(_ga + (size_t)16 * KTOT),        \
                                     (sptr_t)(_la + 512), 16, 0, 0);           \
    __builtin_amdgcn_global_load_lds((gptr_t)_gb, (sptr_t)_lb, 16, 0, 0);      \
    __builtin_amdgcn_global_load_lds((gptr_t)(_gb + (size_t)16 * KTOT),        \
                                     (sptr_t)(_lb + 512), 16, 0, 0);           \
  } while (0)

  // Fragment reads: row base (wm*128 | wn*64) + frag*16 + m16, phys chunk
  // q ^ ((m16>>1)&3) (frag-independent since frag*16 is 0 mod 4 after >>1).
  const int px8 = (q ^ ((m16 >> 1) & 3)) * 8;
  const int aoff = (wm * 128 + m16) * 32 + px8;
  const int boff = (wn * 64 + m16) * 32 + px8;

  bf16x8 fa[8], fb[4];  // current-tile fragments (all indexing fully unrolled)

  // Region T: MFMA with fragments of tile T (in regs) while reloading
  // fragments of tile T+1 from LDS buf (T+1)&3 and staging tile T+4.
#define REGION(T, DOREAD, DOSTAGE, VM)                                         \
  do {                                                                         \
    const u16* _An = &As[(((T) + 1) & 3) * TILE_U16 + aoff];                   \
    const u16* _Bn = &Bs[(((T) + 1) & 3) * TILE_U16 + boff];                   \
    if (DOSTAGE) STAGE((T) + 4);                                               \
    __builtin_amdgcn_s_setprio(1);                                             \
    _Pragma("unroll") for (int mt = 0; mt < 8; ++mt) {                         \
      _Pragma("unroll") for (int nt = 0; nt < 4; ++nt)                         \
        acc[mt][nt] = __builtin_amdgcn_mfma_f32_16x16x32_bf16(                 \
            fa[mt], fb[nt], acc[mt][nt], 0, 0, 0);                             \
      if (DOREAD) fa[mt] = *(const bf16x8*)&_An[mt * 512];                     \
    }                                                                          \
    __builtin_amdgcn_s_setprio(0);                                             \
    if (DOREAD) {                                                              \
      _Pragma("unroll") for (int nt = 0; nt < 4; ++nt)                         \
        fb[nt] = *(const bf16x8*)&_Bn[nt * 512];                               \
    }                                                                          \
    asm volatile("s_waitcnt vmcnt(" #VM ")" ::: "memory");                     \
    asm volatile("s_waitcnt lgkmcnt(0)" ::: "memory");                         \
    __builtin_amdgcn_s_barrier();                                              \
  } while (0)

  // Prologue: fill 4 K-tiles (16 loads/thread); wait until tiles 0,1 landed
  // (vmcnt(8): newest 8 = tiles 2,3); then preload tile-0 fragments.
  STAGE(0);
  STAGE(1);
  STAGE(2);
  STAGE(3);
  asm volatile("s_waitcnt vmcnt(8)" ::: "memory");
  __builtin_amdgcn_s_barrier();
  {
    const u16* _A0 = &As[aoff];
    const u16* _B0 = &Bs[boff];
#pragma unroll
    for (int nt = 0; nt < 4; ++nt) fb[nt] = *(const bf16x8*)&_B0[nt * 512];
#pragma unroll
    for (int mt = 0; mt < 8; ++mt) fa[mt] = *(const bf16x8*)&_A0[mt * 512];
  }

  // Main: regions 0..283 stage tiles 4..287; vmcnt(8) -> tile t+2 landed.
  for (int tb = 0; tb < 71; ++tb) {
#pragma unroll
    for (int j = 0; j < 4; ++j) {
      REGION(tb * 4 + j, true, true, 8);
    }
  }
  // Tail: no more staging; drain 4 -> 0.
  REGION(284, true, false, 4);
  REGION(285, true, false, 0);
  REGION(286, true, false, 0);
  // Region 287: consume-only (fragments of tile 287 already in regs).
  __builtin_amdgcn_s_setprio(1);
#pragma unroll
  for (int mt = 0; mt < 8; ++mt)
#pragma unroll
    for (int nt = 0; nt < 4; ++nt)
      acc[mt][nt] = __builtin_amdgcn_mfma_f32_16x16x32_bf16(fa[mt], fb[nt],
                                                            acc[mt][nt], 0, 0, 0);
  __builtin_amdgcn_s_setprio(0);

#undef REGION
#undef STAGE

  // Epilogue: C/D layout col = lane&15, row = (lane>>4)*4 + reg (m89-verified)
  const int row_base = gy * 256 + wm * 128 + q * 4;
  const int col_base = gx * 256 + wn * 64 + m16;
#pragma unroll
  for (int mt = 0; mt < 8; ++mt) {
#pragma unroll
    for (int nt = 0; nt < 4; ++nt) {
      const int r0 = row_base + mt * 16;
      const int c  = col_base + nt * 16;
#pragma unroll
      for (int r = 0; r < 4; ++r)
        C[(size_t)(r0 + r) * OUT_DIM + c] = acc[mt][nt][r];
    }
  }
}

// ---------------------------------------------------------------------------
// TIER-2 (previous session's best, ws >= 88MB): on-the-fly A, 128^2 tile.
// ---------------------------------------------------------------------------
__global__ __launch_bounds__(256) void kan_prep(const float* __restrict__ x,
                                                const float* __restrict__ coef,
                                                const float* __restrict__ scale_base,
                                                const float* __restrict__ scale_sp,
                                                float* __restrict__ xT,
                                                u16* __restrict__ sil,
                                                u16* __restrict__ wt) {
  const int t = threadIdx.x;

  if (blockIdx.x < TR_BLOCKS) {
    __shared__ float tile[64][65];
    const int bi = blockIdx.x;
    const int n0 = (bi & 127) * 64;
    const int d0 = (bi >> 7) * 64;
    const int col = t & 63, rbase = t >> 6;
#pragma unroll
    for (int i = 0; i < 16; ++i) {
      const int r = rbase + i * 4;
      const float v = x[(size_t)(n0 + r) * IN_DIM + d0 + col];
      tile[r][col] = v;
      sil[(size_t)(n0 + r) * IN_DIM + d0 + col] =
          f2b(v * rcp_fast(1.0f + __expf(-v)));
    }
    __syncthreads();
#pragma unroll
    for (int i = 0; i < 16; ++i) {
      const int dd = rbase + i * 4;
      xT[(size_t)(d0 + dd) * NROWS + n0 + col] = tile[col][dd];
    }
  } else {
    __shared__ __align__(16) u16 tsp[WT_O][WT_D * 8 + 8];
    __shared__ __align__(16) u16 tsi[WT_O][WT_D + 8];
    const int bi = blockIdx.x - TR_BLOCKS;
    const int o0 = (bi % (OUT_DIM / WT_O)) * WT_O;
    const int d0 = (bi / (OUT_DIM / WT_O)) * WT_D;
    const int ol = t & (WT_O - 1), dl0 = t >> 4;
#pragma unroll
    for (int rep = 0; rep < WT_D / 16; ++rep) {
      const int dl = rep * 16 + dl0;
      const int d = d0 + dl, o = o0 + ol;
      const size_t doff = (size_t)d * OUT_DIM + o;
      const float ssp = scale_sp[doff];
      const float sbv = scale_base[doff];
      const float4* cp = (const float4*)(coef + doff * 8);
      float4 c0 = cp[0], c1 = cp[1];
      uint4 val;
      val.x = pkbf(c0.x * ssp, c0.y * ssp);
      val.y = pkbf(c0.z * ssp, c0.w * ssp);
      val.z = pkbf(c1.x * ssp, c1.y * ssp);
      val.w = pkbf(c1.z * ssp, c1.w * ssp);
      *(uint4*)&tsp[ol][dl * 8] = val;
      tsi[ol][dl] = f2b(sbv);
    }
    __syncthreads();
    for (int i = t; i < WT_O * 64; i += 256) {
      const int row = i >> 6, col = i & 63;
      *(uint4*)(wt + (size_t)(o0 + row) * KTOT + (size_t)(d0 + col) * 8) =
          *(const uint4*)&tsp[row][col * 8];
    }
    if (t < WT_O * 8) {
      const int row = t >> 3, col = t & 7;
      *(uint4*)(wt + (size_t)(o0 + row) * KTOT + KSPL + d0 + col * 8) =
          *(const uint4*)&tsi[row][col * 8];
    }
  }
}

__global__ __launch_bounds__(256) void kan_gemm(const float* __restrict__ xT,
                                                const u16* __restrict__ sil,
                                                const u16* __restrict__ Bt,
                                                float* __restrict__ C) {
  __shared__ __align__(16) u16 As[128 * 64];
  __shared__ __align__(16) u16 Bs[128 * 64];
  const int tid  = threadIdx.x;
  const int lane = tid & 63;
  const int w    = tid >> 6;
  const int wm   = w >> 1, wn = w & 1;
  const int q    = lane >> 4, m16 = lane & 15;
  const int gx = blockIdx.x, gy = blockIdx.y;

  f32x4 acc[4][4];
#pragma unroll
  for (int i = 0; i < 4; ++i)
#pragma unroll
    for (int j = 0; j < 4; ++j) acc[i][j] = (f32x4){0.f, 0.f, 0.f, 0.f};

  const int srow = lane >> 3;
  const int swzc = (lane & 7) ^ srow;
  const u16* gb0 = Bt + (size_t)(gx * 128) * KTOT + swzc * 8;
  const int r7 = m16 & 15 & 7;
  const int dgrp = tid >> 5;
  const int nh   = tid & 31;

  for (int kk = 0; kk < KTOT; kk += 64) {
#pragma unroll
    for (int i = 0; i < 4; ++i) {
      const int rg = w * 32 + i * 8;
      __builtin_amdgcn_global_load_lds((gptr_t)(gb0 + (size_t)(rg + srow) * KTOT + kk),
                                       (sptr_t)&Bs[rg * 64], 16, 0, 0);
    }
    if (kk < KSPL) {
      const int d = (kk >> 3) + dgrp;
      const float4 xv = *(const float4*)(xT + (size_t)d * NROWS + gy * 128 + nh * 4);
      const float xa[4] = {xv.x, xv.y, xv.z, xv.w};
#pragma unroll
      for (int r = 0; r < 4; ++r) {
        const int row = nh * 4 + r;
        const uint4 wv = basis_pack(xa[r]);
        *(uint4*)&As[row * 64 + ((dgrp ^ (row & 7)) * 8)] = wv;
      }
    } else {
      const int kb = kk - KSPL;
#pragma unroll
      for (int i = 0; i < 4; ++i) {
        const int rg = w * 32 + i * 8;
        __builtin_amdgcn_global_load_lds(
            (gptr_t)(sil + (size_t)(gy * 128 + rg + srow) * IN_DIM + kb + swzc * 8),
            (sptr_t)&As[rg * 64], 16, 0, 0);
      }
    }
    __syncthreads();
#pragma unroll
    for (int ks = 0; ks < 64; ks += 32) {
      const int pc = ((ks >> 3) + q) ^ r7;
      bf16x8 af[4], bf[4];
#pragma unroll
      for (int mt = 0; mt < 4; ++mt)
        af[mt] = *(const bf16x8*)&As[(wm * 64 + mt * 16 + m16) * 64 + pc * 8];
#pragma unroll
      for (int nt = 0; nt < 4; ++nt)
        bf[nt] = *(const bf16x8*)&Bs[(wn * 64 + nt * 16 + m16) * 64 + pc * 8];
#pragma unroll
      for (int mt = 0; mt < 4; ++mt)
#pragma unroll
        for (int nt = 0; nt < 4; ++nt)
          acc[mt][nt] = __builtin_amdgcn_mfma_f32_16x16x32_bf16(af[mt], bf[nt],
                                                                acc[mt][nt], 0, 0, 0);
    }
    __syncthreads();
  }

#pragma unroll
  for (int mt = 0; mt < 4; ++mt) {
    const int row0 = gy * 128 + wm * 64 + mt * 16 + q * 4;
#pragma unroll
    for (int nt = 0; nt < 4; ++nt) {
      const int col = gx * 128 + wn * 64 + nt * 16 + m16;
#pragma unroll
      for (int r = 0; r < 4; ++r)
        C[(size_t)(row0 + r) * OUT_DIM + col] = acc[mt][nt][r];
    }
  }
}

// ---------------------------------------------------------------------------
// Fallback (workspace too small): fused direct fp32 computation.
// ---------------------------------------------------------------------------
__global__ __launch_bounds__(256) void kan_fallback(const float* __restrict__ x,
                                                    const float* __restrict__ grid,
                                                    const float* __restrict__ coef,
                                                    const float* __restrict__ scale_base,
                                                    const float* __restrict__ scale_sp,
                                                    float* __restrict__ out) {
  __shared__ float bs[IN_DIM * 9];  // 36 KB
  const int n = blockIdx.x;
  const int t = threadIdx.x;
#pragma unroll
  for (int dd = 0; dd < IN_DIM / 256; ++dd) {
    const int d = t + dd * 256;
    const float xv = x[(size_t)n * IN_DIM + d];
    float tt = (xv + 1.0f) * 2.5f;
    float jf = floorf(tt);
    jf = fminf(fmaxf(jf, 0.0f), 4.0f);
    const float u = tt - jf;
    const int j = (int)jf;
    const float um = 1.0f - u;
    const float u2 = u * u, u3 = u2 * u;
    float* r = &bs[d * 9];
#pragma unroll
    for (int g = 0; g < NB; ++g) r[g] = 0.0f;
    r[j]     = um * um * um * (1.0f / 6.0f);
    r[j + 1] = (3.0f * u3 - 6.0f * u2 + 4.0f) * (1.0f / 6.0f);
    r[j + 2] = (-3.0f * u3 + 3.0f * u2 + 3.0f * u + 1.0f) * (1.0f / 6.0f);
    r[j + 3] = u3 * (1.0f / 6.0f);
    r[8]     = xv * rcp_fast(1.0f + __expf(-xv));
  }
  __syncthreads();
  const int o = blockIdx.y * 256 + t;
  float acc = 0.0f;
  for (int d = 0; d < IN_DIM; ++d) {
    const size_t doff = (size_t)d * OUT_DIM + o;
    const float4* cp = (const float4*)(coef + doff * 8);
    float4 c0 = cp[0], c1 = cp[1];
    const float* b = &bs[d * 9];
    float s = b[0] * c0.x + b[1] * c0.y + b[2] * c0.z + b[3] * c0.w +
              b[4] * c1.x + b[5] * c1.y + b[6] * c1.z + b[7] * c1.w;
    acc += s * scale_sp[doff] + b[8] * scale_base[doff];
  }
  out[(size_t)n * OUT_DIM + o] = acc;
}

extern "C" void kernel_launch(void* const* d_in, const int* in_sizes, int n_in,
                              void* d_out, int out_size, void* d_ws, size_t ws_size,
                              hipStream_t stream) {
  const float* x  = (const float*)d_in[0];  // (4,2048,1024)
  const float* gr = (const float*)d_in[1];  // (1024,12)  (uniform; unused in fast path)
  const float* cf = (const float*)d_in[2];  // (1024,2048,8)
  const float* sb = (const float*)d_in[3];  // (1024,2048)
  const float* sp = (const float*)d_in[4];  // (1024,2048)
  float* out = (float*)d_out;               // (4,2048,2048)

  const size_t act_bytes = (size_t)NROWS * KTOT * sizeof(u16);    // 151 MB
  const size_t wt_bytes  = (size_t)OUT_DIM * KTOT * sizeof(u16);  // 37.7 MB
  const size_t need1 = act_bytes + wt_bytes;                      // ~189 MB

  const size_t xT_bytes  = (size_t)IN_DIM * NROWS * sizeof(float);  // 33.5 MB
  const size_t sil_bytes = (size_t)NROWS * IN_DIM * sizeof(u16);    // 16.8 MB
  const size_t need2 = xT_bytes + sil_bytes + wt_bytes;             // ~88 MB

  if (ws_size >= need1) {
    u16* act = (u16*)d_ws;
    u16* wt  = (u16*)((char*)d_ws + act_bytes);
    kan_prep2<<<dim3(ACT2_BLOCKS + WT_BLOCKS), dim3(256), 0, stream>>>(
        x, cf, sb, sp, act, wt);
    kan_gemm2<<<dim3(256), dim3(512), 0, stream>>>(act, wt, out);
  } else if (ws_size >= need2) {
    float* xT = (float*)d_ws;
    u16* sil  = (u16*)((char*)d_ws + xT_bytes);
    u16* wt   = (u16*)((char*)d_ws + xT_bytes + sil_bytes);
    kan_prep<<<dim3(TR_BLOCKS + WT_BLOCKS), dim3(256), 0, stream>>>(
        x, cf, sb, sp, xT, sil, wt);
    kan_gemm<<<dim3(OUT_DIM / 128, NROWS / 128), dim3(256), 0, stream>>>(
        xT, sil, wt, out);
  } else {
    kan_fallback<<<dim3(NROWS, OUT_DIM / 256), dim3(256), 0, stream>>>(x, gr, cf, sb, sp, out);
  }
}

// Round 7
// 430.996 us; speedup vs baseline: 1.1776x; 1.0239x over previous
//
#include <hip/hip_runtime.h>
#include <hip/hip_bf16.h>
#include <cstdint>

typedef unsigned short u16;
typedef __bf16 bf16x8 __attribute__((ext_vector_type(8)));
typedef float  f32x4  __attribute__((ext_vector_type(4)));

typedef const __attribute__((address_space(1))) void* gptr_t;
typedef __attribute__((address_space(3))) void*       sptr_t;

#define IN_DIM  1024
#define OUT_DIM 2048
#define NROWS   8192            // 4*2048 samples
#define NB      8               // GRID + K   (basis functions per d)
#define KTOT    (IN_DIM * 9)    // 9216: k<8192 -> spline d*8+g ; k>=8192 -> silu d
#define KSPL    (IN_DIM * 8)    // 8192

#define WT_O 16                 // wt transpose tile: 16 o x 64 d
#define WT_D 64
#define TR_BLOCKS ((NROWS / 64) * (IN_DIM / 64))        // 2048 x-transpose blocks
#define WT_BLOCKS ((OUT_DIM / WT_O) * (IN_DIM / WT_D))  // 2048 wt blocks

// GEMM geometry: 256x256 tile, BK=32, R3 schedule (rolling reg prefetch).
#define BK 32
#define TILE_U16 (256 * BK)     // 8192 u16 = 16 KB per K-tile buffer (per matrix)
#define NKT (KTOT / BK)         // 288 (tiles 0..255 spline, 256..287 silu)

__device__ __forceinline__ float rcp_fast(float v) { return __builtin_amdgcn_rcpf(v); }

// fp32 -> bf16 round-to-nearest-even bit pattern (finite inputs only)
__device__ __forceinline__ u16 f2b(float v) {
  uint32_t u = __float_as_uint(v);
  uint32_t r = (u + 0x7FFFu + ((u >> 16) & 1u)) >> 16;
  return (u16)r;
}

// pack two fp32 -> packed bf16x2 (a in low half), RNE
__device__ __forceinline__ uint32_t pkbf(float a, float b) {
  return (uint32_t)f2b(a) | ((uint32_t)f2b(b) << 16);
}

// Uniform-knot cardinal cubic: 8 spline channels for one x, packed as 4x u32
// (bf16 pairs, channel g ascending). j=floor((x+1)*2.5) in [0,4], u=frac;
// nonzero channels j..j+3 = {(1-u)^3, 3u^3-6u^2+4, -3u^3+3u^2+3u+1, u^3}/6.
__device__ __forceinline__ uint4 basis_pack(float xval) {
  float tt = (xval + 1.0f) * 2.5f;
  float jf = floorf(tt);
  jf = fminf(fmaxf(jf, 0.0f), 4.0f);
  const float u = tt - jf;
  const int j = (int)jf;
  const float um = 1.0f - u;
  const float u2 = u * u, u3 = u2 * u;
  const float b0 = um * um * um * (1.0f / 6.0f);
  const float b1 = (3.0f * u3 - 6.0f * u2 + 4.0f) * (1.0f / 6.0f);
  const float b2 = (-3.0f * u3 + 3.0f * u2 + 3.0f * u + 1.0f) * (1.0f / 6.0f);
  const float b3 = u3 * (1.0f / 6.0f);
  const uint32_t e01 = pkbf(b0, b1), e23 = pkbf(b2, b3);
  const uint32_t o0 = e01 << 16;                      // (0, h0)
  const uint32_t o12 = (e01 >> 16) | (e23 << 16);     // (h1, h2)
  const uint32_t o3 = e23 >> 16;                      // (h3, 0)
  const int odd = j & 1, m = j >> 1;
  const uint32_t a0 = odd ? o0 : e01;
  const uint32_t a1 = odd ? o12 : e23;
  const uint32_t a2 = odd ? o3 : 0u;
  uint4 wv;
  wv.x = (m == 0) ? a0 : 0u;
  wv.y = (m == 1) ? a0 : ((m == 0) ? a1 : 0u);
  wv.z = (m == 2) ? a0 : ((m == 1) ? a1 : ((m == 0) ? a2 : 0u));
  wv.w = (m == 2) ? a1 : ((m == 1) ? a2 : 0u);
  return wv;
}

// ---------------------------------------------------------------------------
// Prep (tier-2's proven kernel, ~99us measured era): blocks [0,TR_BLOCKS)
// transpose x -> xT[d][n] fp32 + emit sil[n][d] = bf16(silu(x)); blocks
// [TR_BLOCKS,+WT_BLOCKS) build Wt[o][k] bf16. NO act tensor (151 MB write +
// 151 MB gemm fetch deleted; prep measured at ~2.2 TB/s effective, so the
// only real lever is traffic volume).
// ---------------------------------------------------------------------------
__global__ __launch_bounds__(256) void kan_prep(const float* __restrict__ x,
                                                const float* __restrict__ coef,
                                                const float* __restrict__ scale_base,
                                                const float* __restrict__ scale_sp,
                                                float* __restrict__ xT,
                                                u16* __restrict__ sil,
                                                u16* __restrict__ wt) {
  const int t = threadIdx.x;

  if (blockIdx.x < TR_BLOCKS) {
    __shared__ float tile[64][65];
    const int bi = blockIdx.x;
    const int n0 = (bi & 127) * 64;
    const int d0 = (bi >> 7) * 64;
    const int col = t & 63, rbase = t >> 6;
#pragma unroll
    for (int i = 0; i < 16; ++i) {
      const int r = rbase + i * 4;
      const float v = x[(size_t)(n0 + r) * IN_DIM + d0 + col];
      tile[r][col] = v;
      sil[(size_t)(n0 + r) * IN_DIM + d0 + col] =
          f2b(v * rcp_fast(1.0f + __expf(-v)));
    }
    __syncthreads();
#pragma unroll
    for (int i = 0; i < 16; ++i) {
      const int dd = rbase + i * 4;
      xT[(size_t)(d0 + dd) * NROWS + n0 + col] = tile[col][dd];
    }
  } else {
    __shared__ __align__(16) u16 tsp[WT_O][WT_D * 8 + 8];
    __shared__ __align__(16) u16 tsi[WT_O][WT_D + 8];
    const int bi = blockIdx.x - TR_BLOCKS;
    const int o0 = (bi % (OUT_DIM / WT_O)) * WT_O;
    const int d0 = (bi / (OUT_DIM / WT_O)) * WT_D;
    const int ol = t & (WT_O - 1), dl0 = t >> 4;
#pragma unroll
    for (int rep = 0; rep < WT_D / 16; ++rep) {
      const int dl = rep * 16 + dl0;
      const int d = d0 + dl, o = o0 + ol;
      const size_t doff = (size_t)d * OUT_DIM + o;
      const float ssp = scale_sp[doff];
      const float sbv = scale_base[doff];
      const float4* cp = (const float4*)(coef + doff * 8);
      float4 c0 = cp[0], c1 = cp[1];
      uint4 val;
      val.x = pkbf(c0.x * ssp, c0.y * ssp);
      val.y = pkbf(c0.z * ssp, c0.w * ssp);
      val.z = pkbf(c1.x * ssp, c1.y * ssp);
      val.w = pkbf(c1.z * ssp, c1.w * ssp);
      *(uint4*)&tsp[ol][dl * 8] = val;
      tsi[ol][dl] = f2b(sbv);
    }
    __syncthreads();
    for (int i = t; i < WT_O * 64; i += 256) {
      const int row = i >> 6, col = i & 63;
      *(uint4*)(wt + (size_t)(o0 + row) * KTOT + (size_t)(d0 + col) * 8) =
          *(const uint4*)&tsp[row][col * 8];
    }
    if (t < WT_O * 8) {
      const int row = t >> 3, col = t & 7;
      *(uint4*)(wt + (size_t)(o0 + row) * KTOT + KSPL + d0 + col * 8) =
          *(const uint4*)&tsi[row][col * 8];
    }
  }
}

// ---------------------------------------------------------------------------
// Fused GEMM: C = A(x) * Wt^T with A generated IN-KERNEL. R3 schedule kept
// byte-for-byte on the MFMA/frag-read/sync core (two schedule rewrites
// failed; only the staging source changes):
//  - spline K-tiles (T<256): A-tile computed from xT — per thread 2 coalesced
//    fp32 loads + 2 basis_pack + 2 swizzled ds_write_b128, placed AFTER the
//    MFMA cluster so x-load latency hides under the 32 MFMAs. Write distance
//    +2 (R(T) writes A(T+2)); WAR separated by >=2 barriers.
//  - silu K-tiles (T>=256): A via global_load_lds from sil (pre-swizzled
//    source), distance +2, issued BEFORE the B stage so end-of-region
//    vmcnt(2) retires it exactly when R(T+1)'s frag reads need it.
//  - B staged via global_load_lds, distance +3; uniform vmcnt(2)/region.
//    Scalar xT loads share vmcnt but are always older than the newest
//    B-stage, so all waits remain conservative-correct.
// ---------------------------------------------------------------------------
__global__ __launch_bounds__(512, 2) void kan_gemm3(const float* __restrict__ xT,
                                                    const u16* __restrict__ sil,
                                                    const u16* __restrict__ Bt,
                                                    float* __restrict__ C) {
  __shared__ __align__(16) u16 As[4 * TILE_U16];  // 64 KB
  __shared__ __align__(16) u16 Bs[4 * TILE_U16];  // 64 KB
  const int tid  = threadIdx.x;
  const int lane = tid & 63;
  const int w    = tid >> 6;            // 0..7
  const int wm   = w >> 2, wn = w & 3;  // 2 x 4 wave grid
  const int q    = lane >> 4, m16 = lane & 15;

  // Bijective XCD swizzle: 256 wgs = 8 XCDs x 32; gx fastest.
  const int bid = (blockIdx.x & 7) * 32 + (blockIdx.x >> 3);
  const int gx = bid & 7;    // o-tile   (N/256 = 8)
  const int gy = bid >> 3;   // row-tile (M/256 = 32)

  f32x4 acc[8][4];
#pragma unroll
  for (int i = 0; i < 8; ++i)
#pragma unroll
    for (int j = 0; j < 4; ++j) acc[i][j] = (f32x4){0.f, 0.f, 0.f, 0.f};

  // DMA staging lanes (B always; A only for silu tiles): wave w covers rows
  // [w*32,w*32+32), lane l -> row +(l>>2) (+16 on 2nd issue), phys chunk l&3,
  // pre-swizzled source chunk (l&3)^((l>>3)&3).
  const int rA  = lane >> 2;
  const int csw = ((lane & 3) ^ ((lane >> 3) & 3)) * 8;  // u16 offset
  const u16* gB = Bt  + (size_t)(gx * 256 + w * 32 + rA) * KTOT + csw;
  const u16* sA = sil + (size_t)(gy * 256 + w * 32 + rA) * IN_DIM + csw;
  const int ldsw = w * 1024;  // u16 offset of this wave's 32-row segment

  // Spline A-generation lanes: thread owns (row = tid&255, chunks cd0, cd0+2).
  // Stored phys chunk = cd ^ ((row>>1)&3) — matches the frag readers.
  const int arow = tid & 255;
  const int cd0  = tid >> 8;               // 0 or 1
  const int asw  = (arow >> 1) & 3;
  const int aw0  = arow * 32 + (cd0 ^ asw) * 8;
  const int aw1  = arow * 32 + ((cd0 + 2) ^ asw) * 8;
  const float* xp = xT + (size_t)cd0 * NROWS + gy * 256 + arow;  // + d*NROWS

#define STAGE_B(T)                                                             \
  do {                                                                         \
    const int _bb = (T) & 3;                                                   \
    const size_t _k0 = (size_t)(T) * BK;                                       \
    __builtin_amdgcn_global_load_lds((gptr_t)(gB + _k0),                       \
        (sptr_t)&Bs[_bb * TILE_U16 + ldsw], 16, 0, 0);                         \
    __builtin_amdgcn_global_load_lds((gptr_t)(gB + (size_t)16 * KTOT + _k0),   \
        (sptr_t)&Bs[_bb * TILE_U16 + ldsw + 512], 16, 0, 0);                   \
  } while (0)

#define STAGE_A_SIL(T)                                                         \
  do {                                                                         \
    const int _ab = (T) & 3;                                                   \
    const size_t _db = (size_t)(T) * BK - KSPL;                                \
    __builtin_amdgcn_global_load_lds((gptr_t)(sA + _db),                       \
        (sptr_t)&As[_ab * TILE_U16 + ldsw], 16, 0, 0);                         \
    __builtin_amdgcn_global_load_lds((gptr_t)(sA + (size_t)16 * IN_DIM + _db), \
        (sptr_t)&As[_ab * TILE_U16 + ldsw + 512], 16, 0, 0);                   \
  } while (0)

  // Write spline A-tile T (2 chunks/thread) from preloaded x values.
#define WRITE_A_SPL(T, X0, X1)                                                 \
  do {                                                                         \
    const int _ab = (T) & 3;                                                   \
    *(uint4*)&As[_ab * TILE_U16 + aw0] = basis_pack(X0);                       \
    *(uint4*)&As[_ab * TILE_U16 + aw1] = basis_pack(X1);                       \
  } while (0)

  // Fragment read offsets (R3): row base + phys chunk q ^ ((m16>>1)&3).
  const int px8 = (q ^ ((m16 >> 1) & 3)) * 8;
  const int aoff = (wm * 128 + m16) * 32 + px8;
  const int boff = (wn * 64 + m16) * 32 + px8;

  bf16x8 fa[8], fb[4];

  // R3 core: MFMA tile T (fragments in regs) + reload fragments of tile T+1.
#define CORE(T)                                                                \
  do {                                                                         \
    const u16* _An = &As[(((T) + 1) & 3) * TILE_U16 + aoff];                   \
    const u16* _Bn = &Bs[(((T) + 1) & 3) * TILE_U16 + boff];                   \
    __builtin_amdgcn_s_setprio(1);                                             \
    _Pragma("unroll") for (int mt = 0; mt < 8; ++mt) {                         \
      _Pragma("unroll") for (int nt = 0; nt < 4; ++nt)                         \
        acc[mt][nt] = __builtin_amdgcn_mfma_f32_16x16x32_bf16(                 \
            fa[mt], fb[nt], acc[mt][nt], 0, 0, 0);                             \
      fa[mt] = *(const bf16x8*)&_An[mt * 512];                                 \
    }                                                                          \
    __builtin_amdgcn_s_setprio(0);                                             \
    _Pragma("unroll") for (int nt = 0; nt < 4; ++nt)                           \
      fb[nt] = *(const bf16x8*)&_Bn[nt * 512];                                 \
  } while (0)

#define ENDSYNC(VM)                                                            \
  do {                                                                         \
    asm volatile("s_waitcnt vmcnt(" #VM ")" ::: "memory");                     \
    asm volatile("s_waitcnt lgkmcnt(0)" ::: "memory");                         \
    __builtin_amdgcn_s_barrier();                                              \
  } while (0)

  // Spline region T (T <= 253): A(T+2) computed, B(T+3) staged.
#define SP_REGION(T)                                                           \
  do {                                                                         \
    const float _x0 = xp[(size_t)(((T) + 2) * 4) * NROWS];                     \
    const float _x1 = xp[(size_t)(((T) + 2) * 4 + 2) * NROWS];                 \
    STAGE_B((T) + 3);                                                          \
    CORE(T);                                                                   \
    WRITE_A_SPL((T) + 2, _x0, _x1);                                            \
    ENDSYNC(2);                                                                \
  } while (0)

  // Silu region T (254 <= T <= 284): A(T+2) DMA'd (FIRST), B(T+3) staged.
#define SI_REGION(T)                                                           \
  do {                                                                         \
    STAGE_A_SIL((T) + 2);                                                      \
    STAGE_B((T) + 3);                                                          \
    CORE(T);                                                                   \
    ENDSYNC(2);                                                                \
  } while (0)

  // Prologue: stage B(0..2); write spline A(0), A(1); drain; preload frags(0).
  STAGE_B(0);
  STAGE_B(1);
  STAGE_B(2);
  {
    const float x00 = xp[0];
    const float x01 = xp[(size_t)2 * NROWS];
    const float x10 = xp[(size_t)4 * NROWS];
    const float x11 = xp[(size_t)6 * NROWS];
    WRITE_A_SPL(0, x00, x01);
    WRITE_A_SPL(1, x10, x11);
  }
  ENDSYNC(2);   // B(0),B(1) landed; A-writes drained; all waves synced
  {
    const u16* _A0 = &As[aoff];
    const u16* _B0 = &Bs[boff];
#pragma unroll
    for (int nt = 0; nt < 4; ++nt) fb[nt] = *(const bf16x8*)&_B0[nt * 512];
#pragma unroll
    for (int mt = 0; mt < 8; ++mt) fa[mt] = *(const bf16x8*)&_A0[mt * 512];
  }

  // Spline main: T = 0..251 (63 x 4, buffer indices compile-time), 252, 253.
  for (int tb = 0; tb < 63; ++tb) {
#pragma unroll
    for (int j = 0; j < 4; ++j) {
      SP_REGION(tb * 4 + j);
    }
  }
  SP_REGION(252);
  SP_REGION(253);

  // Silu: T = 254, 255, then 256..283 (7 x 4), then 284 (stages last B=287).
  SI_REGION(254);
  SI_REGION(255);
  for (int tb = 0; tb < 7; ++tb) {
#pragma unroll
    for (int j = 0; j < 4; ++j) {
      SI_REGION(256 + tb * 4 + j);
    }
  }
  SI_REGION(284);

  // T=285: stage A(287) only (no more B); everything must land by end.
  STAGE_A_SIL(287);
  CORE(285);
  ENDSYNC(0);
  // T=286: no staging; frag-reads of 287.
  CORE(286);
  asm volatile("s_waitcnt lgkmcnt(0)" ::: "memory");
  __builtin_amdgcn_s_barrier();
  // T=287: consume-only.
  __builtin_amdgcn_s_setprio(1);
#pragma unroll
  for (int mt = 0; mt < 8; ++mt)
#pragma unroll
    for (int nt = 0; nt < 4; ++nt)
      acc[mt][nt] = __builtin_amdgcn_mfma_f32_16x16x32_bf16(fa[mt], fb[nt],
                                                            acc[mt][nt], 0, 0, 0);
  __builtin_amdgcn_s_setprio(0);

#undef SP_REGION
#undef SI_REGION
#undef ENDSYNC
#undef CORE
#undef WRITE_A_SPL
#undef STAGE_A_SIL
#undef STAGE_B

  // Epilogue: C/D layout col = lane&15, row = (lane>>4)*4 + reg (m89-verified)
  const int row_base = gy * 256 + wm * 128 + q * 4;
  const int col_base = gx * 256 + wn * 64 + m16;
#pragma unroll
  for (int mt = 0; mt < 8; ++mt) {
#pragma unroll
    for (int nt = 0; nt < 4; ++nt) {
      const int r0 = row_base + mt * 16;
      const int c  = col_base + nt * 16;
#pragma unroll
      for (int r = 0; r < 4; ++r)
        C[(size_t)(r0 + r) * OUT_DIM + c] = acc[mt][nt][r];
    }
  }
}

// ---------------------------------------------------------------------------
// Fallback (workspace too small): fused direct fp32 computation.
// ---------------------------------------------------------------------------
__global__ __launch_bounds__(256) void kan_fallback(const float* __restrict__ x,
                                                    const float* __restrict__ grid,
                                                    const float* __restrict__ coef,
                                                    const float* __restrict__ scale_base,
                                                    const float* __restrict__ scale_sp,
                                                    float* __restrict__ out) {
  __shared__ float bs[IN_DIM * 9];  // 36 KB
  const int n = blockIdx.x;
  const int t = threadIdx.x;
#pragma unroll
  for (int dd = 0; dd < IN_DIM / 256; ++dd) {
    const int d = t + dd * 256;
    const float xv = x[(size_t)n * IN_DIM + d];
    float tt = (xv + 1.0f) * 2.5f;
    float jf = floorf(tt);
    jf = fminf(fmaxf(jf, 0.0f), 4.0f);
    const float u = tt - jf;
    const int j = (int)jf;
    const float um = 1.0f - u;
    const float u2 = u * u, u3 = u2 * u;
    float* r = &bs[d * 9];
#pragma unroll
    for (int g = 0; g < NB; ++g) r[g] = 0.0f;
    r[j]     = um * um * um * (1.0f / 6.0f);
    r[j + 1] = (3.0f * u3 - 6.0f * u2 + 4.0f) * (1.0f / 6.0f);
    r[j + 2] = (-3.0f * u3 + 3.0f * u2 + 3.0f * u + 1.0f) * (1.0f / 6.0f);
    r[j + 3] = u3 * (1.0f / 6.0f);
    r[8]     = xv * rcp_fast(1.0f + __expf(-xv));
  }
  __syncthreads();
  const int o = blockIdx.y * 256 + t;
  float acc = 0.0f;
  for (int d = 0; d < IN_DIM; ++d) {
    const size_t doff = (size_t)d * OUT_DIM + o;
    const float4* cp = (const float4*)(coef + doff * 8);
    float4 c0 = cp[0], c1 = cp[1];
    const float* b = &bs[d * 9];
    float s = b[0] * c0.x + b[1] * c0.y + b[2] * c0.z + b[3] * c0.w +
              b[4] * c1.x + b[5] * c1.y + b[6] * c1.z + b[7] * c1.w;
    acc += s * scale_sp[doff] + b[8] * scale_base[doff];
  }
  out[(size_t)n * OUT_DIM + o] = acc;
}

extern "C" void kernel_launch(void* const* d_in, const int* in_sizes, int n_in,
                              void* d_out, int out_size, void* d_ws, size_t ws_size,
                              hipStream_t stream) {
  const float* x  = (const float*)d_in[0];  // (4,2048,1024)
  const float* gr = (const float*)d_in[1];  // (1024,12)  (uniform; unused in fast path)
  const float* cf = (const float*)d_in[2];  // (1024,2048,8)
  const float* sb = (const float*)d_in[3];  // (1024,2048)
  const float* sp = (const float*)d_in[4];  // (1024,2048)
  float* out = (float*)d_out;               // (4,2048,2048)

  const size_t xT_bytes  = (size_t)IN_DIM * NROWS * sizeof(float);  // 33.5 MB
  const size_t sil_bytes = (size_t)NROWS * IN_DIM * sizeof(u16);    // 16.8 MB
  const size_t wt_bytes  = (size_t)OUT_DIM * KTOT * sizeof(u16);    // 37.7 MB
  const size_t need = xT_bytes + sil_bytes + wt_bytes;              // ~88 MB

  if (ws_size >= need) {
    float* xT = (float*)d_ws;
    u16* sil  = (u16*)((char*)d_ws + xT_bytes);
    u16* wt   = (u16*)((char*)d_ws + xT_bytes + sil_bytes);
    kan_prep<<<dim3(TR_BLOCKS + WT_BLOCKS), dim3(256), 0, stream>>>(
        x, cf, sb, sp, xT, sil, wt);
    kan_gemm3<<<dim3(256), dim3(512), 0, stream>>>(xT, sil, wt, out);
  } else {
    kan_fallback<<<dim3(NROWS, OUT_DIM / 256), dim3(256), 0, stream>>>(x, gr, cf, sb, sp, out);
  }
}